// Round 1
// baseline (2417.532 us; speedup 1.0000x reference)
//
#include <hip/hip_runtime.h>
#include <hip/hip_bf16.h>

typedef __attribute__((ext_vector_type(4))) float  f32x4;
typedef __attribute__((ext_vector_type(8))) __bf16 bf16x8;
typedef __hip_bfloat16 bf16_t;

#define GT 256
#define BM 128
#define BN 128
#define BK 32

#define AS1Q __attribute__((address_space(1)))
#define AS3Q __attribute__((address_space(3)))

__device__ __forceinline__ void gload_lds16(const void* g, void* l) {
    __builtin_amdgcn_global_load_lds((AS1Q void*)const_cast<void*>(g),
                                     (AS3Q void*)l, 16, 0, 0);
}

// C = A[M,K] * B[N,K]^T   (both row-major, K contiguous), bf16 in, f32 acc.
// EPI 0: Cb[m*N+n] = bf16(relu(acc + vecM[m]))            (fcT output)
// EPI 1: Cf[m*N+n] += acc * vecM[m] * scale   (atomic when gridDim.z>1)
template<int EPI>
__global__ __launch_bounds__(GT)
void gemm_bt(const bf16_t* __restrict__ A, const bf16_t* __restrict__ B,
             int M, int N, int K,
             const float* __restrict__ vecM,
             bf16_t* __restrict__ Cb, float* __restrict__ Cf, float scale)
{
    // LDS layout: row-major [128 rows][4 kc-chunks of 16B], kc XOR-swizzled by (row>>1)&3
    __shared__ bf16_t sA[BM * BK];
    __shared__ bf16_t sB[BN * BK];

    const int tid  = threadIdx.x;
    const int lane = tid & 63;
    const int wid  = tid >> 6;
    const int wr = wid >> 1, wc = wid & 1;       // 2x2 wave grid, 64x64 out each
    const int l15 = lane & 15, lk = lane >> 4;   // fragment lane decomposition

    const long rowA0 = (long)blockIdx.x * BM;
    const long rowB0 = (long)blockIdx.y * BN;
    const long ldab  = (long)K * 2;              // bytes per row

    // staging: 512 chunks of 16B per tile; chunk c -> row=c>>2, kc=c&3.
    // global source kc pre-swizzled so LDS (linear dest) ends up swizzled.
    const int c0 = tid, c1 = tid + GT;
    const int r0c = c0 >> 2, k0c = (c0 & 3) ^ ((r0c >> 1) & 3);
    const int r1c = c1 >> 2, k1c = (c1 & 3) ^ ((r1c >> 1) & 3);

    const char* gA0 = (const char*)A + (rowA0 + r0c) * ldab + k0c * 16;
    const char* gA1 = (const char*)A + (rowA0 + r1c) * ldab + k1c * 16;
    const char* gB0 = (const char*)B + (rowB0 + r0c) * ldab + k0c * 16;
    const char* gB1 = (const char*)B + (rowB0 + r1c) * ldab + k1c * 16;
    char* lA0 = (char*)sA + c0 * 16;
    char* lA1 = (char*)sA + c1 * 16;
    char* lB0 = (char*)sB + c0 * 16;
    char* lB1 = (char*)sB + c1 * 16;

    f32x4 acc[4][4];
    #pragma unroll
    for (int i = 0; i < 4; i++)
        #pragma unroll
        for (int j = 0; j < 4; j++) acc[i][j] = f32x4{0.f, 0.f, 0.f, 0.f};

    const int nz     = gridDim.z;
    const int ktPer  = (K / BK) / nz;
    const long kb0   = (long)(ktPer * blockIdx.z) * (BK * 2);
    gA0 += kb0; gA1 += kb0; gB0 += kb0; gB1 += kb0;

    for (int kt = 0; kt < ktPer; ++kt) {
        const long kByte = (long)kt * (BK * 2);
        gload_lds16(gA0 + kByte, lA0);
        gload_lds16(gA1 + kByte, lA1);
        gload_lds16(gB0 + kByte, lB0);
        gload_lds16(gB1 + kByte, lB1);
        __syncthreads();   // drains vmcnt before use

        bf16x8 af[4], bg[4];
        #pragma unroll
        for (int i = 0; i < 4; i++) {
            const int rr = wr * 64 + i * 16 + l15;
            const int kk = lk ^ ((rr >> 1) & 3);
            af[i] = *reinterpret_cast<const bf16x8*>((const char*)sA + rr * 64 + kk * 16);
        }
        #pragma unroll
        for (int j = 0; j < 4; j++) {
            const int rr = wc * 64 + j * 16 + l15;
            const int kk = lk ^ ((rr >> 1) & 3);
            bg[j] = *reinterpret_cast<const bf16x8*>((const char*)sB + rr * 64 + kk * 16);
        }
        #pragma unroll
        for (int i = 0; i < 4; i++)
            #pragma unroll
            for (int j = 0; j < 4; j++)
                acc[i][j] = __builtin_amdgcn_mfma_f32_16x16x32_bf16(af[i], bg[j], acc[i][j], 0, 0, 0);
        __syncthreads();
    }

    // epilogue: C row m = 4*(lane>>4)+reg (+16*i +64*wr), col n = lane&15 (+16*j +64*wc)
    #pragma unroll
    for (int i = 0; i < 4; i++) {
        const long mBase = rowA0 + wr * 64 + i * 16 + lk * 4;
        const f32x4 vm = *reinterpret_cast<const f32x4*>(&vecM[mBase]);
        #pragma unroll
        for (int r = 0; r < 4; r++) {
            const long m = mBase + r;
            #pragma unroll
            for (int j = 0; j < 4; j++) {
                const long n = rowB0 + wc * 64 + j * 16 + l15;
                float v = acc[i][j][r];
                if constexpr (EPI == 0) {
                    v += vm[r];
                    v = fmaxf(v, 0.f);
                    Cb[m * (long)N + n] = __float2bfloat16(v);
                } else {
                    v *= vm[r] * scale;
                    if (nz == 1) Cf[m * (long)N + n] += v;
                    else atomicAdd(&Cf[m * (long)N + n], v);
                }
            }
        }
    }
}

__global__ __launch_bounds__(256)
void k_cast_bf16(const float* __restrict__ in, bf16_t* __restrict__ out, long n)
{
    const long stride = (long)gridDim.x * blockDim.x;
    for (long i = (long)blockIdx.x * blockDim.x + threadIdx.x; i * 4 < n; i += stride) {
        f32x4 v = *reinterpret_cast<const f32x4*>(in + i * 4);
        union { bf16_t h[4]; ushort4 u; } o;
        o.h[0] = __float2bfloat16(v[0]); o.h[1] = __float2bfloat16(v[1]);
        o.h[2] = __float2bfloat16(v[2]); o.h[3] = __float2bfloat16(v[3]);
        *reinterpret_cast<ushort4*>(out + i * 4) = o.u;
    }
}

// out[c][r] = bf16(in[r][c]); R,C multiples of 32
__global__ __launch_bounds__(256)
void k_transpose_bf16(const float* __restrict__ in, bf16_t* __restrict__ out, int R, int C)
{
    __shared__ float tile[32][33];
    const int tx = threadIdx.x & 31, ty = threadIdx.x >> 5;
    const int c0 = blockIdx.x * 32, r0 = blockIdx.y * 32;
    #pragma unroll
    for (int i = 0; i < 4; i++)
        tile[ty + i * 8][tx] = in[(long)(r0 + ty + i * 8) * C + c0 + tx];
    __syncthreads();
    #pragma unroll
    for (int i = 0; i < 4; i++)
        out[(long)(c0 + ty + i * 8) * R + r0 + tx] = __float2bfloat16(tile[tx][ty + i * 8]);
}

__global__ __launch_bounds__(256)
void k_rowsum_inv(const float* __restrict__ A, float* __restrict__ out, int cols)
{
    const long row = blockIdx.x;
    const float* p = A + row * (long)cols;
    float s = 0.f;
    for (int c = threadIdx.x * 4; c < cols; c += 256 * 4) {
        f32x4 v = *reinterpret_cast<const f32x4*>(p + c);
        s += v[0] + v[1] + v[2] + v[3];
    }
    #pragma unroll
    for (int off = 32; off > 0; off >>= 1) s += __shfl_down(s, off);
    __shared__ float ws4[4];
    if ((threadIdx.x & 63) == 0) ws4[threadIdx.x >> 6] = s;
    __syncthreads();
    if (threadIdx.x == 0) out[row] = 1.0f / (ws4[0] + ws4[1] + ws4[2] + ws4[3] + 1e-7f);
}

__global__ __launch_bounds__(256)
void k_colsum_inv(const float* __restrict__ A, float* __restrict__ out, int rows, int cols)
{
    const int c = blockIdx.x * 256 + threadIdx.x;
    float s = 0.f;
    #pragma unroll 4
    for (int r = 0; r < rows; ++r) s += A[(long)r * cols + c];
    out[c] = 1.0f / (s + 1e-7f);
}

extern "C" void kernel_launch(void* const* d_in, const int* in_sizes, int n_in,
                              void* d_out, int out_size, void* d_ws, size_t ws_size,
                              hipStream_t stream)
{
    if (n_in < 15) return;
    const float* obj_feats = (const float*)d_in[0];
    const float* rel_feats = (const float*)d_in[1];
    const float* attn_sub  = (const float*)d_in[2];
    const float* attn_obj  = (const float*)d_in[3];
    const float* attn_self = (const float*)d_in[4];
    // weight order: rel2obj_sub, rel2obj_obj, obj2rel_sub, obj2rel_obj, obj2obj
    const float* Wf[5] = { (const float*)d_in[5], (const float*)d_in[7],
                           (const float*)d_in[9], (const float*)d_in[11], (const float*)d_in[13] };
    const float* Bf[5] = { (const float*)d_in[6], (const float*)d_in[8],
                           (const float*)d_in[10], (const float*)d_in[12], (const float*)d_in[14] };

    const int NO = 2048, NR = 16384, D = 1024;

    char* w = (char*)d_ws;
    auto take = [&](size_t bytes) { char* p = w; w += bytes; return p; };
    bf16_t* AS_bf    = (bf16_t*)take((size_t)NO * NR * 2);
    bf16_t* AO_bf    = (bf16_t*)take((size_t)NO * NR * 2);
    bf16_t* ASelf_bf = (bf16_t*)take((size_t)NO * NO * 2);
    bf16_t* AST_bf   = (bf16_t*)take((size_t)NR * NO * 2);
    bf16_t* AOT_bf   = (bf16_t*)take((size_t)NR * NO * 2);
    bf16_t* xrel_bf  = (bf16_t*)take((size_t)NR * D * 2);
    bf16_t* xobj_bf  = (bf16_t*)take((size_t)NO * D * 2);
    bf16_t* fcT      = (bf16_t*)take((size_t)D * NR * 2);
    bf16_t* Wb[5];
    for (int i = 0; i < 5; i++) Wb[i] = (bf16_t*)take((size_t)D * D * 2);
    float* inv_d_sub  = (float*)take((size_t)NO * 4);
    float* inv_d_obj  = (float*)take((size_t)NO * 4);
    float* inv_d_self = (float*)take((size_t)NO * 4);
    float* inv_dT_sub = (float*)take((size_t)NR * 4);
    float* inv_dT_obj = (float*)take((size_t)NR * 4);
    if ((size_t)(w - (char*)d_ws) > ws_size) return;   // ws too small: bail visibly

    float* x_obj = (float*)d_out;
    float* x_rel = x_obj + (size_t)NO * D;

    hipMemcpyAsync(x_obj, obj_feats, (size_t)NO * D * 4, hipMemcpyDeviceToDevice, stream);
    hipMemcpyAsync(x_rel, rel_feats, (size_t)NR * D * 4, hipMemcpyDeviceToDevice, stream);

    auto cast = [&](const float* in, bf16_t* out, long n) {
        long blocks = (n / 4 + 255) / 256; if (blocks > 4096) blocks = 4096;
        k_cast_bf16<<<dim3((unsigned)blocks), dim3(256), 0, stream>>>(in, out, n);
    };
    cast(attn_sub,  AS_bf,    (long)NO * NR);
    cast(attn_obj,  AO_bf,    (long)NO * NR);
    cast(attn_self, ASelf_bf, (long)NO * NO);
    for (int i = 0; i < 5; i++) cast(Wf[i], Wb[i], (long)D * D);

    k_transpose_bf16<<<dim3(NR / 32, NO / 32), dim3(256), 0, stream>>>(attn_sub, AST_bf, NO, NR);
    k_transpose_bf16<<<dim3(NR / 32, NO / 32), dim3(256), 0, stream>>>(attn_obj, AOT_bf, NO, NR);

    k_rowsum_inv<<<dim3(NO), dim3(256), 0, stream>>>(attn_sub,  inv_d_sub,  NR);
    k_rowsum_inv<<<dim3(NO), dim3(256), 0, stream>>>(attn_obj,  inv_d_obj,  NR);
    k_rowsum_inv<<<dim3(NO), dim3(256), 0, stream>>>(attn_self, inv_d_self, NO);
    k_colsum_inv<<<dim3(NR / 256), dim3(256), 0, stream>>>(attn_sub, inv_dT_sub, NO, NR);
    k_colsum_inv<<<dim3(NR / 256), dim3(256), 0, stream>>>(attn_obj, inv_dT_obj, NO, NR);

    // fcT[d_out, src] = relu(W @ x^T + b)  == gemm_bt(A=W[D,D], B=x[Nsrc,D])
    auto fc_gemm = [&](const bf16_t* Wbb, const float* bias, const bf16_t* X, int Nsrc) {
        dim3 g(D / BM, Nsrc / BN, 1);
        gemm_bt<0><<<g, dim3(GT), 0, stream>>>(Wbb, X, D, Nsrc, D, bias, fcT, nullptr, 0.f);
    };
    // Xout[m, :] += (attn[m,:] @ fc) * inv_den[m] * scale   == gemm_bt(A=attn, B=fcT)
    auto col_gemm = [&](const bf16_t* Attn, int Ntgt, int Nsrc, const float* invd,
                        float* Xout, float scl, int ksplit) {
        dim3 g(Ntgt / BM, D / BN, ksplit);
        gemm_bt<1><<<g, dim3(GT), 0, stream>>>(Attn, fcT, Ntgt, D, Nsrc, invd, nullptr, Xout, scl);
    };

    for (int step = 0; step < 2; ++step) {
        // snapshots (all GEMMs read these; masters updated in-place afterwards)
        cast(x_obj, xobj_bf, (long)NO * D);
        cast(x_rel, xrel_bf, (long)NR * D);

        fc_gemm(Wb[0], Bf[0], xrel_bf, NR);                                   // rel2obj_sub
        col_gemm(AS_bf, NO, NR, inv_d_sub, x_obj, 1.f / 3.f, 4);
        fc_gemm(Wb[1], Bf[1], xrel_bf, NR);                                   // rel2obj_obj
        col_gemm(AO_bf, NO, NR, inv_d_obj, x_obj, 1.f / 3.f, 4);
        fc_gemm(Wb[4], Bf[4], xobj_bf, NO);                                   // obj2obj
        col_gemm(ASelf_bf, NO, NO, inv_d_self, x_obj, 1.f / 3.f, 4);
        fc_gemm(Wb[2], Bf[2], xobj_bf, NO);                                   // obj2rel_sub
        col_gemm(AST_bf, NR, NO, inv_dT_sub, x_rel, 0.5f, 1);
        fc_gemm(Wb[3], Bf[3], xobj_bf, NO);                                   // obj2rel_obj
        col_gemm(AOT_bf, NR, NO, inv_dT_obj, x_rel, 0.5f, 1);
    }
}

// Round 2
// 1874.147 us; speedup vs baseline: 1.2899x; 1.2899x over previous
//
#include <hip/hip_runtime.h>
#include <hip/hip_bf16.h>

typedef __attribute__((ext_vector_type(4))) float  f32x4;
typedef __attribute__((ext_vector_type(8))) __bf16 bf16x8;
typedef __hip_bfloat16 bf16_t;

#define GT 256
#define BM 128
#define BN 128
#define BK 32

#define AS1Q __attribute__((address_space(1)))
#define AS3Q __attribute__((address_space(3)))

__device__ __forceinline__ void gload_lds16(const void* g, void* l) {
    __builtin_amdgcn_global_load_lds((AS1Q void*)const_cast<void*>(g),
                                     (AS3Q void*)l, 16, 0, 0);
}

// C = A[M,K] * B[N,K]^T   (both row-major, K contiguous), bf16 in, f32 acc.
// EPI 0: Cb[m*N+n] = bf16(relu(acc + vecM[m]))            (fcT output)
// EPI 1: Cf[m*N+n] += acc * vecM[m] * scale   (atomic when gridDim.z>1)
template<int EPI>
__global__ __launch_bounds__(GT)
void gemm_bt(const bf16_t* __restrict__ A, const bf16_t* __restrict__ B,
             int M, int N, int K,
             const float* __restrict__ vecM,
             bf16_t* __restrict__ Cb, float* __restrict__ Cf, float scale)
{
    // LDS layout: row-major [128 rows][4 kc-chunks of 16B], kc XOR-swizzled by (row>>1)&3
    __shared__ bf16_t sA[BM * BK];
    __shared__ bf16_t sB[BN * BK];

    const int tid  = threadIdx.x;
    const int lane = tid & 63;
    const int wid  = tid >> 6;
    const int wr = wid >> 1, wc = wid & 1;       // 2x2 wave grid, 64x64 out each
    const int l15 = lane & 15, lk = lane >> 4;   // fragment lane decomposition

    const long rowA0 = (long)blockIdx.x * BM;
    const long rowB0 = (long)blockIdx.y * BN;
    const long ldab  = (long)K * 2;              // bytes per row

    // staging: 512 chunks of 16B per tile; chunk c -> row=c>>2, kc=c&3.
    // global source kc pre-swizzled so LDS (linear dest) ends up swizzled.
    const int c0 = tid, c1 = tid + GT;
    const int r0c = c0 >> 2, k0c = (c0 & 3) ^ ((r0c >> 1) & 3);
    const int r1c = c1 >> 2, k1c = (c1 & 3) ^ ((r1c >> 1) & 3);

    const char* gA0 = (const char*)A + (rowA0 + r0c) * ldab + k0c * 16;
    const char* gA1 = (const char*)A + (rowA0 + r1c) * ldab + k1c * 16;
    const char* gB0 = (const char*)B + (rowB0 + r0c) * ldab + k0c * 16;
    const char* gB1 = (const char*)B + (rowB0 + r1c) * ldab + k1c * 16;
    char* lA0 = (char*)sA + c0 * 16;
    char* lA1 = (char*)sA + c1 * 16;
    char* lB0 = (char*)sB + c0 * 16;
    char* lB1 = (char*)sB + c1 * 16;

    f32x4 acc[4][4];
    #pragma unroll
    for (int i = 0; i < 4; i++)
        #pragma unroll
        for (int j = 0; j < 4; j++) acc[i][j] = f32x4{0.f, 0.f, 0.f, 0.f};

    const int nz     = gridDim.z;
    const int ktPer  = (K / BK) / nz;
    const long kb0   = (long)(ktPer * blockIdx.z) * (BK * 2);
    gA0 += kb0; gA1 += kb0; gB0 += kb0; gB1 += kb0;

    for (int kt = 0; kt < ktPer; ++kt) {
        const long kByte = (long)kt * (BK * 2);
        gload_lds16(gA0 + kByte, lA0);
        gload_lds16(gA1 + kByte, lA1);
        gload_lds16(gB0 + kByte, lB0);
        gload_lds16(gB1 + kByte, lB1);
        __syncthreads();   // drains vmcnt before use

        bf16x8 af[4], bg[4];
        #pragma unroll
        for (int i = 0; i < 4; i++) {
            const int rr = wr * 64 + i * 16 + l15;
            const int kk = lk ^ ((rr >> 1) & 3);
            af[i] = *reinterpret_cast<const bf16x8*>((const char*)sA + rr * 64 + kk * 16);
        }
        #pragma unroll
        for (int j = 0; j < 4; j++) {
            const int rr = wc * 64 + j * 16 + l15;
            const int kk = lk ^ ((rr >> 1) & 3);
            bg[j] = *reinterpret_cast<const bf16x8*>((const char*)sB + rr * 64 + kk * 16);
        }
        #pragma unroll
        for (int i = 0; i < 4; i++)
            #pragma unroll
            for (int j = 0; j < 4; j++)
                acc[i][j] = __builtin_amdgcn_mfma_f32_16x16x32_bf16(af[i], bg[j], acc[i][j], 0, 0, 0);
        __syncthreads();
    }

    // epilogue: C row m = 4*(lane>>4)+reg (+16*i +64*wr), col n = lane&15 (+16*j +64*wc)
    #pragma unroll
    for (int i = 0; i < 4; i++) {
        const long mBase = rowA0 + wr * 64 + i * 16 + lk * 4;
        const f32x4 vm = *reinterpret_cast<const f32x4*>(&vecM[mBase]);
        #pragma unroll
        for (int r = 0; r < 4; r++) {
            const long m = mBase + r;
            #pragma unroll
            for (int j = 0; j < 4; j++) {
                const long n = rowB0 + wc * 64 + j * 16 + l15;
                float v = acc[i][j][r];
                if constexpr (EPI == 0) {
                    v += vm[r];
                    v = fmaxf(v, 0.f);
                    Cb[m * (long)N + n] = __float2bfloat16(v);
                } else {
                    v *= vm[r] * scale;
                    if (nz == 1) Cf[m * (long)N + n] += v;
                    else atomicAdd(&Cf[m * (long)N + n], v);
                }
            }
        }
    }
}

__global__ __launch_bounds__(256)
void k_cast_bf16(const float* __restrict__ in, bf16_t* __restrict__ out, long n)
{
    const long stride = (long)gridDim.x * blockDim.x;
    for (long i = (long)blockIdx.x * blockDim.x + threadIdx.x; i * 4 < n; i += stride) {
        f32x4 v = *reinterpret_cast<const f32x4*>(in + i * 4);
        union { bf16_t h[4]; ushort4 u; } o;
        o.h[0] = __float2bfloat16(v[0]); o.h[1] = __float2bfloat16(v[1]);
        o.h[2] = __float2bfloat16(v[2]); o.h[3] = __float2bfloat16(v[3]);
        *reinterpret_cast<ushort4*>(out + i * 4) = o.u;
    }
}

// Fused prologue: read f32 attn [R,C] once per tile; emit bf16 copy, bf16
// transpose (optional), row-sum partials and col-sum partials (atomicAdd into
// pre-zeroed buffers). 64x64 f32 tile per block, 256 threads.
template<bool TRANS>
__global__ __launch_bounds__(256)
void k_prep_attn(const float* __restrict__ in, int R, int C,
                 bf16_t* __restrict__ outb, bf16_t* __restrict__ outT,
                 float* __restrict__ rowsum, float* __restrict__ colsum)
{
    __shared__ float tile[64][65];
    __shared__ float cpart[16][64];
    __shared__ float rpart[64][17];

    const int tid = threadIdx.x;
    const int tx  = tid & 15;      // col quad index (cols tx*4 .. tx*4+3)
    const int ty  = tid >> 4;      // 0..15 row-within-group
    const long c0 = (long)blockIdx.x * 64;
    const long r0 = (long)blockIdx.y * 64;

    float cs0 = 0.f, cs1 = 0.f, cs2 = 0.f, cs3 = 0.f;

    #pragma unroll
    for (int i = 0; i < 4; i++) {
        const int r = i * 16 + ty;
        const f32x4 v = *reinterpret_cast<const f32x4*>(&in[(r0 + r) * (long)C + c0 + tx * 4]);
        // bf16 straight copy (coalesced 8B/lane)
        union { bf16_t h[4]; ushort4 u; } o;
        o.h[0] = __float2bfloat16(v[0]); o.h[1] = __float2bfloat16(v[1]);
        o.h[2] = __float2bfloat16(v[2]); o.h[3] = __float2bfloat16(v[3]);
        *reinterpret_cast<ushort4*>(&outb[(r0 + r) * (long)C + c0 + tx * 4]) = o.u;
        // stash f32 for transpose + rowsum
        *reinterpret_cast<f32x4*>(&tile[r][tx * 4]) = v;
        cs0 += v[0]; cs1 += v[1]; cs2 += v[2]; cs3 += v[3];
        rpart[r][tx] = v[0] + v[1] + v[2] + v[3];
    }
    if (TRANS) {
        cpart[ty][tx * 4 + 0] = cs0;
        cpart[ty][tx * 4 + 1] = cs1;
        cpart[ty][tx * 4 + 2] = cs2;
        cpart[ty][tx * 4 + 3] = cs3;
    }
    __syncthreads();

    if (tid < 64) {
        float rs = 0.f;
        #pragma unroll
        for (int k = 0; k < 16; k++) rs += rpart[tid][k];
        atomicAdd(&rowsum[r0 + tid], rs);
        if (TRANS) {
            float cssum = 0.f;
            #pragma unroll
            for (int k = 0; k < 16; k++) cssum += cpart[k][tid];
            atomicAdd(&colsum[c0 + tid], cssum);
        }
    }

    if (TRANS) {
        // transposed bf16 write: outT[(c0+c)*R + r0 + rr], rr = lane for coalescing
        const int rr = tid & 63;
        const int cg = tid >> 6;    // 0..3
        #pragma unroll
        for (int i = 0; i < 16; i++) {
            const int c = cg * 16 + i;
            outT[(c0 + c) * (long)R + r0 + rr] = __float2bfloat16(tile[rr][c]);
        }
    }
}

__global__ __launch_bounds__(256)
void k_invert_eps(float* __restrict__ s, int n)
{
    const int i = blockIdx.x * 256 + threadIdx.x;
    if (i < n) s[i] = 1.0f / (s[i] + 1e-7f);
}

extern "C" void kernel_launch(void* const* d_in, const int* in_sizes, int n_in,
                              void* d_out, int out_size, void* d_ws, size_t ws_size,
                              hipStream_t stream)
{
    if (n_in < 15) return;
    const float* obj_feats = (const float*)d_in[0];
    const float* rel_feats = (const float*)d_in[1];
    const float* attn_sub  = (const float*)d_in[2];
    const float* attn_obj  = (const float*)d_in[3];
    const float* attn_self = (const float*)d_in[4];
    // weight order: rel2obj_sub, rel2obj_obj, obj2rel_sub, obj2rel_obj, obj2obj
    const float* Wf[5] = { (const float*)d_in[5], (const float*)d_in[7],
                           (const float*)d_in[9], (const float*)d_in[11], (const float*)d_in[13] };
    const float* Bf[5] = { (const float*)d_in[6], (const float*)d_in[8],
                           (const float*)d_in[10], (const float*)d_in[12], (const float*)d_in[14] };

    const int NO = 2048, NR = 16384, D = 1024;

    char* w = (char*)d_ws;
    auto take = [&](size_t bytes) { char* p = w; w += bytes; return p; };
    bf16_t* AS_bf    = (bf16_t*)take((size_t)NO * NR * 2);
    bf16_t* AO_bf    = (bf16_t*)take((size_t)NO * NR * 2);
    bf16_t* ASelf_bf = (bf16_t*)take((size_t)NO * NO * 2);
    bf16_t* AST_bf   = (bf16_t*)take((size_t)NR * NO * 2);
    bf16_t* AOT_bf   = (bf16_t*)take((size_t)NR * NO * 2);
    bf16_t* xrel_bf  = (bf16_t*)take((size_t)NR * D * 2);
    bf16_t* xobj_bf  = (bf16_t*)take((size_t)NO * D * 2);
    bf16_t* fcT      = (bf16_t*)take((size_t)D * NR * 2);
    bf16_t* Wb[5];
    for (int i = 0; i < 5; i++) Wb[i] = (bf16_t*)take((size_t)D * D * 2);
    // contiguous sums block: [inv_d_sub NO][inv_d_obj NO][inv_d_self NO][inv_dT_sub NR][inv_dT_obj NR]
    float* sums = (float*)take((size_t)(3 * NO + 2 * NR) * 4);
    float* inv_d_sub  = sums;
    float* inv_d_obj  = sums + NO;
    float* inv_d_self = sums + 2 * NO;
    float* inv_dT_sub = sums + 3 * NO;
    float* inv_dT_obj = sums + 3 * NO + NR;
    if ((size_t)(w - (char*)d_ws) > ws_size) return;   // ws too small: bail visibly

    float* x_obj = (float*)d_out;
    float* x_rel = x_obj + (size_t)NO * D;

    hipMemcpyAsync(x_obj, obj_feats, (size_t)NO * D * 4, hipMemcpyDeviceToDevice, stream);
    hipMemcpyAsync(x_rel, rel_feats, (size_t)NR * D * 4, hipMemcpyDeviceToDevice, stream);
    hipMemsetAsync(sums, 0, (size_t)(3 * NO + 2 * NR) * 4, stream);

    auto cast = [&](const float* in, bf16_t* out, long n) {
        long blocks = (n / 4 + 255) / 256; if (blocks > 4096) blocks = 4096;
        k_cast_bf16<<<dim3((unsigned)blocks), dim3(256), 0, stream>>>(in, out, n);
    };
    for (int i = 0; i < 5; i++) cast(Wf[i], Wb[i], (long)D * D);

    // fused cast + transpose + row/col sums
    k_prep_attn<true><<<dim3(NR / 64, NO / 64), dim3(256), 0, stream>>>(
        attn_sub, NO, NR, AS_bf, AST_bf, inv_d_sub, inv_dT_sub);
    k_prep_attn<true><<<dim3(NR / 64, NO / 64), dim3(256), 0, stream>>>(
        attn_obj, NO, NR, AO_bf, AOT_bf, inv_d_obj, inv_dT_obj);
    k_prep_attn<false><<<dim3(NO / 64, NO / 64), dim3(256), 0, stream>>>(
        attn_self, NO, NO, ASelf_bf, nullptr, inv_d_self, nullptr);
    {
        const int n = 3 * NO + 2 * NR;
        k_invert_eps<<<dim3((n + 255) / 256), dim3(256), 0, stream>>>(sums, n);
    }

    // fcT[d_out, src] = relu(W @ x^T + b)  == gemm_bt(A=W[D,D], B=x[Nsrc,D])
    auto fc_gemm = [&](const bf16_t* Wbb, const float* bias, const bf16_t* X, int Nsrc) {
        dim3 g(D / BM, Nsrc / BN, 1);
        gemm_bt<0><<<g, dim3(GT), 0, stream>>>(Wbb, X, D, Nsrc, D, bias, fcT, nullptr, 0.f);
    };
    // Xout[m, :] += (attn[m,:] @ fc) * inv_den[m] * scale   == gemm_bt(A=attn, B=fcT)
    auto col_gemm = [&](const bf16_t* Attn, int Ntgt, int Nsrc, const float* invd,
                        float* Xout, float scl, int ksplit) {
        dim3 g(Ntgt / BM, D / BN, ksplit);
        gemm_bt<1><<<g, dim3(GT), 0, stream>>>(Attn, fcT, Ntgt, D, Nsrc, invd, nullptr, Xout, scl);
    };

    for (int step = 0; step < 2; ++step) {
        // snapshots (all GEMMs read these; masters updated in-place afterwards)
        cast(x_obj, xobj_bf, (long)NO * D);
        cast(x_rel, xrel_bf, (long)NR * D);

        fc_gemm(Wb[0], Bf[0], xrel_bf, NR);                                   // rel2obj_sub
        col_gemm(AS_bf, NO, NR, inv_d_sub, x_obj, 1.f / 3.f, 4);
        fc_gemm(Wb[1], Bf[1], xrel_bf, NR);                                   // rel2obj_obj
        col_gemm(AO_bf, NO, NR, inv_d_obj, x_obj, 1.f / 3.f, 4);
        fc_gemm(Wb[4], Bf[4], xobj_bf, NO);                                   // obj2obj
        col_gemm(ASelf_bf, NO, NO, inv_d_self, x_obj, 1.f / 3.f, 4);
        fc_gemm(Wb[2], Bf[2], xobj_bf, NO);                                   // obj2rel_sub
        col_gemm(AST_bf, NR, NO, inv_dT_sub, x_rel, 0.5f, 1);
        fc_gemm(Wb[3], Bf[3], xobj_bf, NO);                                   // obj2rel_obj
        col_gemm(AOT_bf, NR, NO, inv_dT_obj, x_rel, 0.5f, 1);
    }
}

// Round 3
// 1399.872 us; speedup vs baseline: 1.7270x; 1.3388x over previous
//
#include <hip/hip_runtime.h>
#include <hip/hip_bf16.h>

typedef __attribute__((ext_vector_type(4))) float  f32x4;
typedef __attribute__((ext_vector_type(8))) __bf16 bf16x8;
typedef __hip_bfloat16 bf16_t;

#define GT 256
#define BM 128
#define BN 128
#define BK 32

#define AS1Q __attribute__((address_space(1)))
#define AS3Q __attribute__((address_space(3)))

__device__ __forceinline__ void gload_lds16(const void* g, void* l) {
    __builtin_amdgcn_global_load_lds((AS1Q void*)const_cast<void*>(g),
                                     (AS3Q void*)l, 16, 0, 0);
}

// ---------------------------------------------------------------------------
// 128x128 2-phase kernel (proven) — kept for the small GEMMs.
// C = A[M,K] * B[N,K]^T, bf16 in, f32 acc.
// EPI 0: Cb = bf16(relu(acc + vecM[m]));  EPI 1: Cf += acc*vecM[m]*scale
// ---------------------------------------------------------------------------
template<int EPI>
__global__ __launch_bounds__(GT)
void gemm_bt(const bf16_t* __restrict__ A, const bf16_t* __restrict__ B,
             int M, int N, int K,
             const float* __restrict__ vecM,
             bf16_t* __restrict__ Cb, float* __restrict__ Cf, float scale)
{
    __shared__ bf16_t sA[BM * BK];
    __shared__ bf16_t sB[BN * BK];

    const int tid  = threadIdx.x;
    const int lane = tid & 63;
    const int wid  = tid >> 6;
    const int wr = wid >> 1, wc = wid & 1;
    const int l15 = lane & 15, lk = lane >> 4;

    const long rowA0 = (long)blockIdx.x * BM;
    const long rowB0 = (long)blockIdx.y * BN;
    const long ldab  = (long)K * 2;

    const int c0 = tid, c1 = tid + GT;
    const int r0c = c0 >> 2, k0c = (c0 & 3) ^ ((r0c >> 1) & 3);
    const int r1c = c1 >> 2, k1c = (c1 & 3) ^ ((r1c >> 1) & 3);

    const char* gA0 = (const char*)A + (rowA0 + r0c) * ldab + k0c * 16;
    const char* gA1 = (const char*)A + (rowA0 + r1c) * ldab + k1c * 16;
    const char* gB0 = (const char*)B + (rowB0 + r0c) * ldab + k0c * 16;
    const char* gB1 = (const char*)B + (rowB0 + r1c) * ldab + k1c * 16;
    char* lA0 = (char*)sA + c0 * 16;
    char* lA1 = (char*)sA + c1 * 16;
    char* lB0 = (char*)sB + c0 * 16;
    char* lB1 = (char*)sB + c1 * 16;

    f32x4 acc[4][4];
    #pragma unroll
    for (int i = 0; i < 4; i++)
        #pragma unroll
        for (int j = 0; j < 4; j++) acc[i][j] = f32x4{0.f, 0.f, 0.f, 0.f};

    const int nz     = gridDim.z;
    const int ktPer  = (K / BK) / nz;
    const long kb0   = (long)(ktPer * blockIdx.z) * (BK * 2);
    gA0 += kb0; gA1 += kb0; gB0 += kb0; gB1 += kb0;

    for (int kt = 0; kt < ktPer; ++kt) {
        const long kByte = (long)kt * (BK * 2);
        gload_lds16(gA0 + kByte, lA0);
        gload_lds16(gA1 + kByte, lA1);
        gload_lds16(gB0 + kByte, lB0);
        gload_lds16(gB1 + kByte, lB1);
        __syncthreads();

        bf16x8 af[4], bg[4];
        #pragma unroll
        for (int i = 0; i < 4; i++) {
            const int rr = wr * 64 + i * 16 + l15;
            const int kk = lk ^ ((rr >> 1) & 3);
            af[i] = *reinterpret_cast<const bf16x8*>((const char*)sA + rr * 64 + kk * 16);
        }
        #pragma unroll
        for (int j = 0; j < 4; j++) {
            const int rr = wc * 64 + j * 16 + l15;
            const int kk = lk ^ ((rr >> 1) & 3);
            bg[j] = *reinterpret_cast<const bf16x8*>((const char*)sB + rr * 64 + kk * 16);
        }
        #pragma unroll
        for (int i = 0; i < 4; i++)
            #pragma unroll
            for (int j = 0; j < 4; j++)
                acc[i][j] = __builtin_amdgcn_mfma_f32_16x16x32_bf16(af[i], bg[j], acc[i][j], 0, 0, 0);
        __syncthreads();
    }

    #pragma unroll
    for (int i = 0; i < 4; i++) {
        const long mBase = rowA0 + wr * 64 + i * 16 + lk * 4;
        const f32x4 vm = *reinterpret_cast<const f32x4*>(&vecM[mBase]);
        #pragma unroll
        for (int r = 0; r < 4; r++) {
            const long m = mBase + r;
            #pragma unroll
            for (int j = 0; j < 4; j++) {
                const long n = rowB0 + wc * 64 + j * 16 + l15;
                float v = acc[i][j][r];
                if constexpr (EPI == 0) {
                    v += vm[r];
                    v = fmaxf(v, 0.f);
                    Cb[m * (long)N + n] = __float2bfloat16(v);
                } else {
                    v *= vm[r] * scale;
                    if (nz == 1) Cf[m * (long)N + n] += v;
                    else atomicAdd(&Cf[m * (long)N + n], v);
                }
            }
        }
    }
}

// ---------------------------------------------------------------------------
// 256x256 8-phase kernel (T2+T3+T4+T5).  512 thr = 8 waves (2M x 4N).
// Per wave: M-frags kf=0..7 at rows wr*16+kf*32; N-frags j at cols wc*16+j*64.
// LDS per buffer: A[256][64] @0, B[256][64] @32768; dbuf at +65536 (128 KiB).
// Swizzle: 16B-chunk ^= (row&7); staged via inverse-swizzled global source.
// Stage stream per tile t (into nxt, for tile t+1): {B0,B1,A0,A1}, one/phase.
// Waits: end of phase1 vmcnt(4) (A-half1 of cur landed); end of phase3
// vmcnt(2) (B0,B1,A0 of next landed). Last tile: vmcnt(0) drains.
// ---------------------------------------------------------------------------
#define DO_PHASE(KF0, KF1, STAGE_STMT, WAIT_STMT)                              \
  {                                                                            \
    bf16x8 af0k0 = *(const bf16x8*)(lcur + baseA + (KF0)*4096 + xo0);          \
    bf16x8 af0k1 = *(const bf16x8*)(lcur + baseA + (KF0)*4096 + xo1);          \
    bf16x8 af1k0 = *(const bf16x8*)(lcur + baseA + (KF1)*4096 + xo0);          \
    bf16x8 af1k1 = *(const bf16x8*)(lcur + baseA + (KF1)*4096 + xo1);          \
    STAGE_STMT;                                                                \
    __builtin_amdgcn_s_barrier();                                              \
    asm volatile("s_waitcnt lgkmcnt(0)" ::: "memory");                         \
    __builtin_amdgcn_sched_barrier(0);                                         \
    __builtin_amdgcn_s_setprio(1);                                             \
    _Pragma("unroll")                                                          \
    for (int j = 0; j < 4; j++) {                                              \
      acc[KF0][j] = __builtin_amdgcn_mfma_f32_16x16x32_bf16(af0k0, bfr[j][0], acc[KF0][j], 0, 0, 0); \
      acc[KF0][j] = __builtin_amdgcn_mfma_f32_16x16x32_bf16(af0k1, bfr[j][1], acc[KF0][j], 0, 0, 0); \
      acc[KF1][j] = __builtin_amdgcn_mfma_f32_16x16x32_bf16(af1k0, bfr[j][0], acc[KF1][j], 0, 0, 0); \
      acc[KF1][j] = __builtin_amdgcn_mfma_f32_16x16x32_bf16(af1k1, bfr[j][1], acc[KF1][j], 0, 0, 0); \
    }                                                                          \
    __builtin_amdgcn_s_setprio(0);                                             \
    WAIT_STMT;                                                                 \
    __builtin_amdgcn_s_barrier();                                              \
  }

template<int EPI>
__global__ __launch_bounds__(512, 2)
void gemm256(const bf16_t* __restrict__ A, const bf16_t* __restrict__ B,
             int M, int N, int K, const float* __restrict__ vecM,
             bf16_t* __restrict__ Cb, float* __restrict__ Cf, float scale,
             int Ntiles)
{
    __shared__ __align__(16) char lds[131072];

    const int tid  = threadIdx.x;
    const int lane = tid & 63;
    const int wid  = tid >> 6;
    const int wr = wid >> 2, wc = wid & 3;
    const int l15 = lane & 15, lk = lane >> 4;

    // XCD-aware bijective swizzle (gridDim.x always a multiple of 8 here)
    const int nwg = gridDim.x;
    const int cpx = nwg >> 3;
    const int bid = blockIdx.x;
    const int swz = (bid & 7) * cpx + (bid >> 3);
    const int tm = swz / Ntiles, tn = swz % Ntiles;
    const long rowM0 = (long)tm * 256;
    const long rowN0 = (long)tn * 256;
    const long ld = (long)K * 2;

    const int nz = gridDim.z;
    const int NT = (K >> 6) / nz;
    const long kb0 = (long)NT * blockIdx.z * 128;   // bytes: NT tiles * 128B

    // staging: thread covers dest bytes tid*16 (+8192) of each 16 KiB half-tile
    const int rl = tid >> 3;                    // dest row 0..63 (load 0)
    const int lc = (tid & 7) ^ (rl & 7);        // inverse-swizzled source chunk
    const char* gA0 = (const char*)A + (rowM0 + rl) * ld + kb0 + lc * 16;
    const char* gB0 = (const char*)B + (rowN0 + rl) * ld + kb0 + lc * 16;

    auto stage = [&](int buf, int isB, int h, int t) {
        const char* g = (isB ? gB0 : gA0) + (long)h * 128 * ld + (long)t * 128;
        char* l = (char*)lds + buf * 65536 + isB * 32768 + h * 16384 + tid * 16;
        gload_lds16(g, l);
        gload_lds16(g + 64 * ld, l + 8192);
    };

    // swizzled ds_read offsets
    const int xo0 = ((0 + lk) ^ (l15 & 7)) * 16;
    const int xo1 = ((4 + lk) ^ (l15 & 7)) * 16;
    const int baseA = (wr * 16 + l15) * 128;
    const int baseB = 32768 + (wc * 16 + l15) * 128;

    f32x4 acc[8][4];
    #pragma unroll
    for (int i = 0; i < 8; i++)
        #pragma unroll
        for (int j = 0; j < 4; j++) acc[i][j] = f32x4{0.f, 0.f, 0.f, 0.f};

    // prologue: stage tile 0 {B0,B1,A0,A1}; A1 may stay in flight
    stage(0, 1, 0, 0); stage(0, 1, 1, 0); stage(0, 0, 0, 0); stage(0, 0, 1, 0);
    asm volatile("s_waitcnt vmcnt(2)" ::: "memory");
    __builtin_amdgcn_sched_barrier(0);
    __builtin_amdgcn_s_barrier();

    bf16x8 bfr[4][2];
    for (int t = 0; t < NT; ++t) {
        const int cur = t & 1;
        const int nxt = cur ^ 1;
        const bool pf = (t + 1) < NT;
        const char* lcur = (const char*)lds + (cur << 16);

        // phase 0: all B-frags + A quad0 (rows <128 for both waves)
        #pragma unroll
        for (int j = 0; j < 4; j++) {
            bfr[j][0] = *(const bf16x8*)(lcur + baseB + j * 8192 + xo0);
            bfr[j][1] = *(const bf16x8*)(lcur + baseB + j * 8192 + xo1);
        }
        DO_PHASE(0, 1, if (pf) stage(nxt, 1, 0, t + 1), );
        // phase 1: quad1 (A-half0); then ensure A-half1(cur) landed
        DO_PHASE(2, 3, if (pf) stage(nxt, 1, 1, t + 1),
                 if (pf) { asm volatile("s_waitcnt vmcnt(4)" ::: "memory"); }
                 else    { asm volatile("s_waitcnt vmcnt(0)" ::: "memory"); }
                 __builtin_amdgcn_sched_barrier(0));
        // phase 2: quad2 (A-half1)
        DO_PHASE(4, 5, if (pf) stage(nxt, 0, 0, t + 1), );
        // phase 3: quad3; then ensure B0,B1,A0(next) landed
        DO_PHASE(6, 7, if (pf) stage(nxt, 0, 1, t + 1),
                 if (pf) { asm volatile("s_waitcnt vmcnt(2)" ::: "memory"); }
                 else    { asm volatile("s_waitcnt vmcnt(0)" ::: "memory"); }
                 __builtin_amdgcn_sched_barrier(0));
    }

    // epilogue: m = rowM0 + wr*16 + kf*32 + lk*4 + r ; n = rowN0 + wc*16 + j*64 + l15
    #pragma unroll
    for (int kf = 0; kf < 8; kf++) {
        const long m0 = rowM0 + wr * 16 + kf * 32 + lk * 4;
        const f32x4 vm = *reinterpret_cast<const f32x4*>(vecM + m0);
        #pragma unroll
        for (int r = 0; r < 4; r++) {
            const long m = m0 + r;
            #pragma unroll
            for (int j = 0; j < 4; j++) {
                const long n = rowN0 + wc * 16 + j * 64 + l15;
                float v = acc[kf][j][r];
                if constexpr (EPI == 0) {
                    v = fmaxf(v + vm[r], 0.f);
                    Cb[m * (long)N + n] = __float2bfloat16(v);
                } else {
                    v *= vm[r] * scale;
                    if (nz == 1) Cf[m * (long)N + n] += v;
                    else atomicAdd(&Cf[m * (long)N + n], v);
                }
            }
        }
    }
}

__global__ __launch_bounds__(256)
void k_cast_bf16(const float* __restrict__ in, bf16_t* __restrict__ out, long n)
{
    const long stride = (long)gridDim.x * blockDim.x;
    for (long i = (long)blockIdx.x * blockDim.x + threadIdx.x; i * 4 < n; i += stride) {
        f32x4 v = *reinterpret_cast<const f32x4*>(in + i * 4);
        union { bf16_t h[4]; ushort4 u; } o;
        o.h[0] = __float2bfloat16(v[0]); o.h[1] = __float2bfloat16(v[1]);
        o.h[2] = __float2bfloat16(v[2]); o.h[3] = __float2bfloat16(v[3]);
        *reinterpret_cast<ushort4*>(out + i * 4) = o.u;
    }
}

template<bool TRANS>
__global__ __launch_bounds__(256)
void k_prep_attn(const float* __restrict__ in, int R, int C,
                 bf16_t* __restrict__ outb, bf16_t* __restrict__ outT,
                 float* __restrict__ rowsum, float* __restrict__ colsum)
{
    __shared__ float tile[64][65];
    __shared__ float cpart[16][64];
    __shared__ float rpart[64][17];

    const int tid = threadIdx.x;
    const int tx  = tid & 15;
    const int ty  = tid >> 4;
    const long c0 = (long)blockIdx.x * 64;
    const long r0 = (long)blockIdx.y * 64;

    float cs0 = 0.f, cs1 = 0.f, cs2 = 0.f, cs3 = 0.f;

    #pragma unroll
    for (int i = 0; i < 4; i++) {
        const int r = i * 16 + ty;
        const f32x4 v = *reinterpret_cast<const f32x4*>(&in[(r0 + r) * (long)C + c0 + tx * 4]);
        union { bf16_t h[4]; ushort4 u; } o;
        o.h[0] = __float2bfloat16(v[0]); o.h[1] = __float2bfloat16(v[1]);
        o.h[2] = __float2bfloat16(v[2]); o.h[3] = __float2bfloat16(v[3]);
        *reinterpret_cast<ushort4*>(&outb[(r0 + r) * (long)C + c0 + tx * 4]) = o.u;
        *reinterpret_cast<f32x4*>(&tile[r][tx * 4]) = v;
        cs0 += v[0]; cs1 += v[1]; cs2 += v[2]; cs3 += v[3];
        rpart[r][tx] = v[0] + v[1] + v[2] + v[3];
    }
    if (TRANS) {
        cpart[ty][tx * 4 + 0] = cs0;
        cpart[ty][tx * 4 + 1] = cs1;
        cpart[ty][tx * 4 + 2] = cs2;
        cpart[ty][tx * 4 + 3] = cs3;
    }
    __syncthreads();

    if (tid < 64) {
        float rs = 0.f;
        #pragma unroll
        for (int k = 0; k < 16; k++) rs += rpart[tid][k];
        atomicAdd(&rowsum[r0 + tid], rs);
        if (TRANS) {
            float cssum = 0.f;
            #pragma unroll
            for (int k = 0; k < 16; k++) cssum += cpart[k][tid];
            atomicAdd(&colsum[c0 + tid], cssum);
        }
    }

    if (TRANS) {
        const int rr = tid & 63;
        const int cg = tid >> 6;
        #pragma unroll
        for (int i = 0; i < 16; i++) {
            const int c = cg * 16 + i;
            outT[(c0 + c) * (long)R + r0 + rr] = __float2bfloat16(tile[rr][c]);
        }
    }
}

__global__ __launch_bounds__(256)
void k_invert_eps(float* __restrict__ s, int n)
{
    const int i = blockIdx.x * 256 + threadIdx.x;
    if (i < n) s[i] = 1.0f / (s[i] + 1e-7f);
}

extern "C" void kernel_launch(void* const* d_in, const int* in_sizes, int n_in,
                              void* d_out, int out_size, void* d_ws, size_t ws_size,
                              hipStream_t stream)
{
    if (n_in < 15) return;
    const float* obj_feats = (const float*)d_in[0];
    const float* rel_feats = (const float*)d_in[1];
    const float* attn_sub  = (const float*)d_in[2];
    const float* attn_obj  = (const float*)d_in[3];
    const float* attn_self = (const float*)d_in[4];
    const float* Wf[5] = { (const float*)d_in[5], (const float*)d_in[7],
                           (const float*)d_in[9], (const float*)d_in[11], (const float*)d_in[13] };
    const float* Bf[5] = { (const float*)d_in[6], (const float*)d_in[8],
                           (const float*)d_in[10], (const float*)d_in[12], (const float*)d_in[14] };

    const int NO = 2048, NR = 16384, D = 1024;

    char* w = (char*)d_ws;
    auto take = [&](size_t bytes) { char* p = w; w += bytes; return p; };
    bf16_t* AS_bf    = (bf16_t*)take((size_t)NO * NR * 2);
    bf16_t* AO_bf    = (bf16_t*)take((size_t)NO * NR * 2);
    bf16_t* ASelf_bf = (bf16_t*)take((size_t)NO * NO * 2);
    bf16_t* AST_bf   = (bf16_t*)take((size_t)NR * NO * 2);
    bf16_t* AOT_bf   = (bf16_t*)take((size_t)NR * NO * 2);
    bf16_t* xrel_bf  = (bf16_t*)take((size_t)NR * D * 2);
    bf16_t* xobj_bf  = (bf16_t*)take((size_t)NO * D * 2);
    bf16_t* fcT      = (bf16_t*)take((size_t)D * NR * 2);   // also holds [3*D][NO]
    bf16_t* Wb0      = (bf16_t*)take((size_t)D * D * 2);
    bf16_t* Wb1      = (bf16_t*)take((size_t)D * D * 2);
    bf16_t* Wstk     = (bf16_t*)take((size_t)3 * D * D * 2);
    float*  bstk     = (float*)take((size_t)3 * D * 4);
    float* sums = (float*)take((size_t)(3 * NO + 2 * NR) * 4);
    float* inv_d_sub  = sums;
    float* inv_d_obj  = sums + NO;
    float* inv_d_self = sums + 2 * NO;
    float* inv_dT_sub = sums + 3 * NO;
    float* inv_dT_obj = sums + 3 * NO + NR;
    if ((size_t)(w - (char*)d_ws) > ws_size) return;

    float* x_obj = (float*)d_out;
    float* x_rel = x_obj + (size_t)NO * D;

    hipMemcpyAsync(x_obj, obj_feats, (size_t)NO * D * 4, hipMemcpyDeviceToDevice, stream);
    hipMemcpyAsync(x_rel, rel_feats, (size_t)NR * D * 4, hipMemcpyDeviceToDevice, stream);
    for (int i = 0; i < 3; i++)
        hipMemcpyAsync(bstk + i * D, Bf[2 + i], (size_t)D * 4, hipMemcpyDeviceToDevice, stream);
    hipMemsetAsync(sums, 0, (size_t)(3 * NO + 2 * NR) * 4, stream);

    auto cast = [&](const float* in, bf16_t* out, long n) {
        long blocks = (n / 4 + 255) / 256; if (blocks > 4096) blocks = 4096;
        k_cast_bf16<<<dim3((unsigned)blocks), dim3(256), 0, stream>>>(in, out, n);
    };
    cast(Wf[0], Wb0, (long)D * D);
    cast(Wf[1], Wb1, (long)D * D);
    cast(Wf[2], Wstk,             (long)D * D);   // obj2rel_sub -> fcT3 rows [0,D)
    cast(Wf[3], Wstk + (size_t)D * D,     (long)D * D);   // obj2rel_obj -> [D,2D)
    cast(Wf[4], Wstk + (size_t)2 * D * D, (long)D * D);   // obj2obj     -> [2D,3D)

    k_prep_attn<true><<<dim3(NR / 64, NO / 64), dim3(256), 0, stream>>>(
        attn_sub, NO, NR, AS_bf, AST_bf, inv_d_sub, inv_dT_sub);
    k_prep_attn<true><<<dim3(NR / 64, NO / 64), dim3(256), 0, stream>>>(
        attn_obj, NO, NR, AO_bf, AOT_bf, inv_d_obj, inv_dT_obj);
    k_prep_attn<false><<<dim3(NO / 64, NO / 64), dim3(256), 0, stream>>>(
        attn_self, NO, NO, ASelf_bf, nullptr, inv_d_self, nullptr);
    {
        const int n = 3 * NO + 2 * NR;
        k_invert_eps<<<dim3((n + 255) / 256), dim3(256), 0, stream>>>(sums, n);
    }

    for (int step = 0; step < 2; ++step) {
        cast(x_obj, xobj_bf, (long)NO * D);
        cast(x_rel, xrel_bf, (long)NR * D);

        // rel->obj (sub): fcT[D][NR] = relu(W0 @ xrel^T + b0); x_obj += (AS@fcT^T)*invd/3
        gemm256<0><<<dim3((D / 256) * (NR / 256), 1, 1), dim3(512), 0, stream>>>(
            Wb0, xrel_bf, D, NR, D, Bf[0], fcT, nullptr, 0.f, NR / 256);
        gemm256<1><<<dim3((NO / 256) * (D / 256), 1, 8), dim3(512), 0, stream>>>(
            AS_bf, fcT, NO, D, NR, inv_d_sub, nullptr, x_obj, 1.f / 3.f, D / 256);

        // rel->obj (obj)
        gemm256<0><<<dim3((D / 256) * (NR / 256), 1, 1), dim3(512), 0, stream>>>(
            Wb1, xrel_bf, D, NR, D, Bf[1], fcT, nullptr, 0.f, NR / 256);
        gemm256<1><<<dim3((NO / 256) * (D / 256), 1, 8), dim3(512), 0, stream>>>(
            AO_bf, fcT, NO, D, NR, inv_d_obj, nullptr, x_obj, 1.f / 3.f, D / 256);

        // obj-side stacked FC: fcT3[3D][NO] = relu(Wstk @ xobj^T + bstk)
        gemm_bt<0><<<dim3(3 * D / BM, NO / BN, 1), dim3(GT), 0, stream>>>(
            Wstk, xobj_bf, 3 * D, NO, D, bstk, fcT, nullptr, 0.f);

        // obj->obj (self), uses fcT3 rows [2D,3D)
        gemm_bt<1><<<dim3(NO / BM, D / BN, 4), dim3(GT), 0, stream>>>(
            ASelf_bf, fcT + (size_t)2 * D * NO, NO, D, NO, inv_d_self, nullptr, x_obj, 1.f / 3.f);

        // obj->rel (sub/obj), use fcT3 rows [0,D) and [D,2D)
        gemm256<1><<<dim3((NR / 256) * (D / 256), 1, 1), dim3(512), 0, stream>>>(
            AST_bf, fcT, NR, D, NO, inv_dT_sub, nullptr, x_rel, 0.5f, D / 256);
        gemm256<1><<<dim3((NR / 256) * (D / 256), 1, 1), dim3(512), 0, stream>>>(
            AOT_bf, fcT + (size_t)D * NO, NR, D, NO, inv_dT_obj, nullptr, x_rel, 0.5f, D / 256);
    }
}

// Round 4
// 1175.870 us; speedup vs baseline: 2.0560x; 1.1905x over previous
//
#include <hip/hip_runtime.h>
#include <hip/hip_bf16.h>

typedef __attribute__((ext_vector_type(4))) float  f32x4;
typedef __attribute__((ext_vector_type(8))) __bf16 bf16x8;
typedef __hip_bfloat16 bf16_t;

#define GT 256
#define BM 128
#define BN 128
#define BK 32

// problem constants
#define NOBJ 2048
#define NREL 16384
#define DIM  1024
#define KOBJ 34816   /* 16384 + 16384 + 2048 */
#define KREL 4096    /* 2048 + 2048 */

#define AS1Q __attribute__((address_space(1)))
#define AS3Q __attribute__((address_space(3)))

__device__ __forceinline__ void gload_lds16(const void* g, void* l) {
    __builtin_amdgcn_global_load_lds((AS1Q void*)const_cast<void*>(g),
                                     (AS3Q void*)l, 16, 0, 0);
}

// ---------------------------------------------------------------------------
// 128x128 2-phase kernel — used once per step for the stacked obj-side FCs.
// C = A[M,K]*B[N,K]^T; epilogue routes rows to fcRel (f2,f3) / fcObj (f4):
//   m <1024: fcRel[m][n]; m<2048: fcRel[m-1024][2048+n]; else fcObj[m-2048][32768+n]
// v = bf16(relu(acc + vecM[m]))
// ---------------------------------------------------------------------------
__global__ __launch_bounds__(GT)
void gemm_bt_f234(const bf16_t* __restrict__ A, const bf16_t* __restrict__ B,
                  int M, int N, int K, const float* __restrict__ vecM,
                  bf16_t* __restrict__ fcRel, bf16_t* __restrict__ fcObj)
{
    __shared__ bf16_t sA[BM * BK];
    __shared__ bf16_t sB[BN * BK];

    const int tid  = threadIdx.x;
    const int lane = tid & 63;
    const int wid  = tid >> 6;
    const int wr = wid >> 1, wc = wid & 1;
    const int l15 = lane & 15, lk = lane >> 4;

    const long rowA0 = (long)blockIdx.x * BM;
    const long rowB0 = (long)blockIdx.y * BN;
    const long ldab  = (long)K * 2;

    const int c0 = tid, c1 = tid + GT;
    const int r0c = c0 >> 2, k0c = (c0 & 3) ^ ((r0c >> 1) & 3);
    const int r1c = c1 >> 2, k1c = (c1 & 3) ^ ((r1c >> 1) & 3);

    const char* gA0 = (const char*)A + (rowA0 + r0c) * ldab + k0c * 16;
    const char* gA1 = (const char*)A + (rowA0 + r1c) * ldab + k1c * 16;
    const char* gB0 = (const char*)B + (rowB0 + r0c) * ldab + k0c * 16;
    const char* gB1 = (const char*)B + (rowB0 + r1c) * ldab + k1c * 16;
    char* lA0 = (char*)sA + c0 * 16;
    char* lA1 = (char*)sA + c1 * 16;
    char* lB0 = (char*)sB + c0 * 16;
    char* lB1 = (char*)sB + c1 * 16;

    f32x4 acc[4][4];
    #pragma unroll
    for (int i = 0; i < 4; i++)
        #pragma unroll
        for (int j = 0; j < 4; j++) acc[i][j] = f32x4{0.f, 0.f, 0.f, 0.f};

    const int ktPer = K / BK;
    for (int kt = 0; kt < ktPer; ++kt) {
        const long kByte = (long)kt * (BK * 2);
        gload_lds16(gA0 + kByte, lA0);
        gload_lds16(gA1 + kByte, lA1);
        gload_lds16(gB0 + kByte, lB0);
        gload_lds16(gB1 + kByte, lB1);
        __syncthreads();

        bf16x8 af[4], bg[4];
        #pragma unroll
        for (int i = 0; i < 4; i++) {
            const int rr = wr * 64 + i * 16 + l15;
            const int kk = lk ^ ((rr >> 1) & 3);
            af[i] = *reinterpret_cast<const bf16x8*>((const char*)sA + rr * 64 + kk * 16);
        }
        #pragma unroll
        for (int j = 0; j < 4; j++) {
            const int rr = wc * 64 + j * 16 + l15;
            const int kk = lk ^ ((rr >> 1) & 3);
            bg[j] = *reinterpret_cast<const bf16x8*>((const char*)sB + rr * 64 + kk * 16);
        }
        #pragma unroll
        for (int i = 0; i < 4; i++)
            #pragma unroll
            for (int j = 0; j < 4; j++)
                acc[i][j] = __builtin_amdgcn_mfma_f32_16x16x32_bf16(af[i], bg[j], acc[i][j], 0, 0, 0);
        __syncthreads();
    }

    #pragma unroll
    for (int i = 0; i < 4; i++) {
        const long mBase = rowA0 + wr * 64 + i * 16 + lk * 4;
        const f32x4 vm = *reinterpret_cast<const f32x4*>(&vecM[mBase]);
        #pragma unroll
        for (int r = 0; r < 4; r++) {
            const long m = mBase + r;
            #pragma unroll
            for (int j = 0; j < 4; j++) {
                const long n = rowB0 + wc * 16 * 0 + wc * 64 + j * 16 + l15;
                const float v = fmaxf(acc[i][j][r] + vm[r], 0.f);
                const bf16_t o = __float2bfloat16(v);
                if (m < 1024)            fcRel[m * (long)KREL + n] = o;
                else if (m < 2048)       fcRel[(m - 1024) * (long)KREL + 2048 + n] = o;
                else                     fcObj[(m - 2048) * (long)KOBJ + 32768 + n] = o;
            }
        }
    }
}

// ---------------------------------------------------------------------------
// 256x256 8-phase kernel (T2+T3+T4+T5).  512 thr = 8 waves (2M x 4N).
// EPI 1: Cf[m*ldc+n] += acc   (atomicAdd when gridDim.z>1; scales pre-folded)
// EPI 2: Cb[(m&1023)*ldc + (m>>10)*16384 + n] = bf16(relu(acc+vecM[m]))
//        (stacked f0/f1 FC routing into fcObj column slices)
// ---------------------------------------------------------------------------
#define DO_PHASE(KF0, KF1, STAGE_STMT, WAIT_STMT)                              \
  {                                                                            \
    bf16x8 af0k0 = *(const bf16x8*)(lcur + baseA + (KF0)*4096 + xo0);          \
    bf16x8 af0k1 = *(const bf16x8*)(lcur + baseA + (KF0)*4096 + xo1);          \
    bf16x8 af1k0 = *(const bf16x8*)(lcur + baseA + (KF1)*4096 + xo0);          \
    bf16x8 af1k1 = *(const bf16x8*)(lcur + baseA + (KF1)*4096 + xo1);          \
    STAGE_STMT;                                                                \
    __builtin_amdgcn_s_barrier();                                              \
    asm volatile("s_waitcnt lgkmcnt(0)" ::: "memory");                         \
    __builtin_amdgcn_sched_barrier(0);                                         \
    __builtin_amdgcn_s_setprio(1);                                             \
    _Pragma("unroll")                                                          \
    for (int j = 0; j < 4; j++) {                                              \
      acc[KF0][j] = __builtin_amdgcn_mfma_f32_16x16x32_bf16(af0k0, bfr[j][0], acc[KF0][j], 0, 0, 0); \
      acc[KF0][j] = __builtin_amdgcn_mfma_f32_16x16x32_bf16(af0k1, bfr[j][1], acc[KF0][j], 0, 0, 0); \
      acc[KF1][j] = __builtin_amdgcn_mfma_f32_16x16x32_bf16(af1k0, bfr[j][0], acc[KF1][j], 0, 0, 0); \
      acc[KF1][j] = __builtin_amdgcn_mfma_f32_16x16x32_bf16(af1k1, bfr[j][1], acc[KF1][j], 0, 0, 0); \
    }                                                                          \
    __builtin_amdgcn_s_setprio(0);                                             \
    WAIT_STMT;                                                                 \
    __builtin_amdgcn_s_barrier();                                              \
  }

template<int EPI>
__global__ __launch_bounds__(512, 2)
void gemm256(const bf16_t* __restrict__ A, const bf16_t* __restrict__ B,
             int M, int N, int K, const float* __restrict__ vecM,
             bf16_t* __restrict__ Cb, float* __restrict__ Cf,
             int ldc, int Ntiles)
{
    __shared__ __align__(16) char lds[131072];

    const int tid  = threadIdx.x;
    const int lane = tid & 63;
    const int wid  = tid >> 6;
    const int wr = wid >> 2, wc = wid & 3;
    const int l15 = lane & 15, lk = lane >> 4;

    const int nwg = gridDim.x;
    const int cpx = nwg >> 3;
    const int bid = blockIdx.x;
    const int swz = (bid & 7) * cpx + (bid >> 3);
    const int tm = swz / Ntiles, tn = swz % Ntiles;
    const long rowM0 = (long)tm * 256;
    const long rowN0 = (long)tn * 256;
    const long ld = (long)K * 2;

    const int nz = gridDim.z;
    const int NT = (K >> 6) / nz;
    const long kb0 = (long)NT * blockIdx.z * 128;

    const int rl = tid >> 3;
    const int lc = (tid & 7) ^ (rl & 7);
    const char* gA0 = (const char*)A + (rowM0 + rl) * ld + kb0 + lc * 16;
    const char* gB0 = (const char*)B + (rowN0 + rl) * ld + kb0 + lc * 16;

    auto stage = [&](int buf, int isB, int h, int t) {
        const char* g = (isB ? gB0 : gA0) + (long)h * 128 * ld + (long)t * 128;
        char* l = (char*)lds + buf * 65536 + isB * 32768 + h * 16384 + tid * 16;
        gload_lds16(g, l);
        gload_lds16(g + 64 * ld, l + 8192);
    };

    const int xo0 = ((0 + lk) ^ (l15 & 7)) * 16;
    const int xo1 = ((4 + lk) ^ (l15 & 7)) * 16;
    const int baseA = (wr * 16 + l15) * 128;
    const int baseB = 32768 + (wc * 16 + l15) * 128;

    f32x4 acc[8][4];
    #pragma unroll
    for (int i = 0; i < 8; i++)
        #pragma unroll
        for (int j = 0; j < 4; j++) acc[i][j] = f32x4{0.f, 0.f, 0.f, 0.f};

    stage(0, 1, 0, 0); stage(0, 1, 1, 0); stage(0, 0, 0, 0); stage(0, 0, 1, 0);
    asm volatile("s_waitcnt vmcnt(2)" ::: "memory");
    __builtin_amdgcn_sched_barrier(0);
    __builtin_amdgcn_s_barrier();

    bf16x8 bfr[4][2];
    for (int t = 0; t < NT; ++t) {
        const int cur = t & 1;
        const int nxt = cur ^ 1;
        const bool pf = (t + 1) < NT;
        const char* lcur = (const char*)lds + (cur << 16);

        #pragma unroll
        for (int j = 0; j < 4; j++) {
            bfr[j][0] = *(const bf16x8*)(lcur + baseB + j * 8192 + xo0);
            bfr[j][1] = *(const bf16x8*)(lcur + baseB + j * 8192 + xo1);
        }
        DO_PHASE(0, 1, if (pf) stage(nxt, 1, 0, t + 1), );
        DO_PHASE(2, 3, if (pf) stage(nxt, 1, 1, t + 1),
                 if (pf) { asm volatile("s_waitcnt vmcnt(4)" ::: "memory"); }
                 else    { asm volatile("s_waitcnt vmcnt(0)" ::: "memory"); }
                 __builtin_amdgcn_sched_barrier(0));
        DO_PHASE(4, 5, if (pf) stage(nxt, 0, 0, t + 1), );
        DO_PHASE(6, 7, if (pf) stage(nxt, 0, 1, t + 1),
                 if (pf) { asm volatile("s_waitcnt vmcnt(2)" ::: "memory"); }
                 else    { asm volatile("s_waitcnt vmcnt(0)" ::: "memory"); }
                 __builtin_amdgcn_sched_barrier(0));
    }

    #pragma unroll
    for (int kf = 0; kf < 8; kf++) {
        const long m0 = rowM0 + wr * 16 + kf * 32 + lk * 4;
        f32x4 vm = f32x4{0.f, 0.f, 0.f, 0.f};
        if constexpr (EPI == 2) vm = *reinterpret_cast<const f32x4*>(vecM + m0);
        #pragma unroll
        for (int r = 0; r < 4; r++) {
            const long m = m0 + r;
            #pragma unroll
            for (int j = 0; j < 4; j++) {
                const long n = rowN0 + wc * 16 + j * 64 + l15;
                const float v = acc[kf][j][r];
                if constexpr (EPI == 1) {
                    if (nz == 1) Cf[m * (long)ldc + n] += v;
                    else atomicAdd(&Cf[m * (long)ldc + n], v);
                } else {
                    const float o = fmaxf(v + vm[r], 0.f);
                    Cb[(m & 1023) * (long)ldc + (m >> 10) * 16384 + n] = __float2bfloat16(o);
                }
            }
        }
    }
}

__global__ __launch_bounds__(256)
void k_cast_bf16(const float* __restrict__ in, bf16_t* __restrict__ out, long n)
{
    const long stride = (long)gridDim.x * blockDim.x;
    for (long i = (long)blockIdx.x * blockDim.x + threadIdx.x; i * 4 < n; i += stride) {
        f32x4 v = *reinterpret_cast<const f32x4*>(in + i * 4);
        union { bf16_t h[4]; ushort4 u; } o;
        o.h[0] = __float2bfloat16(v[0]); o.h[1] = __float2bfloat16(v[1]);
        o.h[2] = __float2bfloat16(v[2]); o.h[3] = __float2bfloat16(v[3]);
        *reinterpret_cast<ushort4*>(out + i * 4) = o.u;
    }
}

// Pass 1: row-sum (+ optional col-sum) partials of f32 attn via atomics.
template<bool COLS>
__global__ __launch_bounds__(256)
void k_sums(const float* __restrict__ in, int C,
            float* __restrict__ rowsum, float* __restrict__ colsum)
{
    __shared__ float cpart[16][64];
    __shared__ float rpart[64][17];
    const int tid = threadIdx.x;
    const int tx  = tid & 15;
    const int ty  = tid >> 4;
    const long c0 = (long)blockIdx.x * 64;
    const long r0 = (long)blockIdx.y * 64;

    float cs0 = 0.f, cs1 = 0.f, cs2 = 0.f, cs3 = 0.f;
    #pragma unroll
    for (int i = 0; i < 4; i++) {
        const int r = i * 16 + ty;
        const f32x4 v = *reinterpret_cast<const f32x4*>(&in[(r0 + r) * (long)C + c0 + tx * 4]);
        rpart[r][tx] = v[0] + v[1] + v[2] + v[3];
        cs0 += v[0]; cs1 += v[1]; cs2 += v[2]; cs3 += v[3];
    }
    if (COLS) {
        cpart[ty][tx * 4 + 0] = cs0;
        cpart[ty][tx * 4 + 1] = cs1;
        cpart[ty][tx * 4 + 2] = cs2;
        cpart[ty][tx * 4 + 3] = cs3;
    }
    __syncthreads();
    if (tid < 64) {
        float rs = 0.f;
        #pragma unroll
        for (int k = 0; k < 16; k++) rs += rpart[tid][k];
        atomicAdd(&rowsum[r0 + tid], rs);
        if (COLS) {
            float cs = 0.f;
            #pragma unroll
            for (int k = 0; k < 16; k++) cs += cpart[k][tid];
            atomicAdd(&colsum[c0 + tid], cs);
        }
    }
}

__global__ __launch_bounds__(256)
void k_invscale(float* __restrict__ s, int n, float c)
{
    const int i = blockIdx.x * 256 + threadIdx.x;
    if (i < n) s[i] = c / (s[i] + 1e-7f);
}

// Pass 2: scaled bf16 write into concat layouts.
// Aobj[(r0+r)*KOBJ + c] = bf16(v * invRow[r0+r])          (ptr pre-offset by col slice)
// Arel[(c0+c)*KREL + r] = bf16(v * invCol[c0+c])          (ptr pre-offset by k slice)
template<bool TRANS>
__global__ __launch_bounds__(256)
void k_prep2(const float* __restrict__ in, int C,
             bf16_t* __restrict__ Aobj, bf16_t* __restrict__ Arel,
             const float* __restrict__ invRow, const float* __restrict__ invCol)
{
    __shared__ float tile[64][65];
    const int tid = threadIdx.x;
    const int tx  = tid & 15;
    const int ty  = tid >> 4;
    const long c0 = (long)blockIdx.x * 64;
    const long r0 = (long)blockIdx.y * 64;

    #pragma unroll
    for (int i = 0; i < 4; i++) {
        const int r = i * 16 + ty;
        const f32x4 v = *reinterpret_cast<const f32x4*>(&in[(r0 + r) * (long)C + c0 + tx * 4]);
        const float sc = invRow[r0 + r];
        union { bf16_t h[4]; ushort4 u; } o;
        o.h[0] = __float2bfloat16(v[0] * sc); o.h[1] = __float2bfloat16(v[1] * sc);
        o.h[2] = __float2bfloat16(v[2] * sc); o.h[3] = __float2bfloat16(v[3] * sc);
        *reinterpret_cast<ushort4*>(&Aobj[(r0 + r) * (long)KOBJ + c0 + tx * 4]) = o.u;
        if (TRANS) *reinterpret_cast<f32x4*>(&tile[r][tx * 4]) = v;
    }
    if (TRANS) {
        __syncthreads();
        const int rr = tid & 63;
        const int cg = tid >> 6;
        #pragma unroll
        for (int i = 0; i < 16; i++) {
            const int c = cg * 16 + i;
            const float sc = invCol[c0 + c];
            Arel[(c0 + c) * (long)KREL + r0 + rr] = __float2bfloat16(tile[rr][c] * sc);
        }
    }
}

extern "C" void kernel_launch(void* const* d_in, const int* in_sizes, int n_in,
                              void* d_out, int out_size, void* d_ws, size_t ws_size,
                              hipStream_t stream)
{
    if (n_in < 15) return;
    const float* obj_feats = (const float*)d_in[0];
    const float* rel_feats = (const float*)d_in[1];
    const float* attn_sub  = (const float*)d_in[2];
    const float* attn_obj  = (const float*)d_in[3];
    const float* attn_self = (const float*)d_in[4];
    const float* Wf[5] = { (const float*)d_in[5], (const float*)d_in[7],
                           (const float*)d_in[9], (const float*)d_in[11], (const float*)d_in[13] };
    const float* Bf[5] = { (const float*)d_in[6], (const float*)d_in[8],
                           (const float*)d_in[10], (const float*)d_in[12], (const float*)d_in[14] };

    const int NO = NOBJ, NR = NREL, D = DIM;

    char* w = (char*)d_ws;
    auto take = [&](size_t bytes) { char* p = w; w += bytes; return p; };
    bf16_t* Aobj    = (bf16_t*)take((size_t)NO * KOBJ * 2);     // [2048][34816]
    bf16_t* Arel    = (bf16_t*)take((size_t)NR * KREL * 2);     // [16384][4096]
    bf16_t* fcObj   = (bf16_t*)take((size_t)D * KOBJ * 2);      // [1024][34816]
    bf16_t* fcRel   = (bf16_t*)take((size_t)D * KREL * 2);      // [1024][4096]
    bf16_t* xrel_bf = (bf16_t*)take((size_t)NR * D * 2);
    bf16_t* xobj_bf = (bf16_t*)take((size_t)NO * D * 2);
    bf16_t* Wstk01  = (bf16_t*)take((size_t)2 * D * D * 2);     // [W0;W1]
    bf16_t* Wstk234 = (bf16_t*)take((size_t)3 * D * D * 2);     // [W2;W3;W4]
    float*  b01     = (float*)take((size_t)2 * D * 4);
    float*  bstk    = (float*)take((size_t)3 * D * 4);
    float*  sums    = (float*)take((size_t)(3 * NO + 2 * NR) * 4);
    float* invS     = sums;            // 1/(3(rowsum_AS+eps))
    float* invO     = sums + NO;
    float* invSelf  = sums + 2 * NO;
    float* invTS    = sums + 3 * NO;   // 0.5/(colsum_AS+eps)
    float* invTO    = sums + 3 * NO + NR;
    if ((size_t)(w - (char*)d_ws) > ws_size) return;   // ws too small: fail loudly

    float* x_obj = (float*)d_out;
    float* x_rel = x_obj + (size_t)NO * D;

    hipMemcpyAsync(x_obj, obj_feats, (size_t)NO * D * 4, hipMemcpyDeviceToDevice, stream);
    hipMemcpyAsync(x_rel, rel_feats, (size_t)NR * D * 4, hipMemcpyDeviceToDevice, stream);
    hipMemcpyAsync(b01,     Bf[0], (size_t)D * 4, hipMemcpyDeviceToDevice, stream);
    hipMemcpyAsync(b01 + D, Bf[1], (size_t)D * 4, hipMemcpyDeviceToDevice, stream);
    for (int i = 0; i < 3; i++)
        hipMemcpyAsync(bstk + i * D, Bf[2 + i], (size_t)D * 4, hipMemcpyDeviceToDevice, stream);
    hipMemsetAsync(sums, 0, (size_t)(3 * NO + 2 * NR) * 4, stream);

    auto cast = [&](const float* in, bf16_t* out, long n) {
        long blocks = (n / 4 + 255) / 256; if (blocks > 4096) blocks = 4096;
        k_cast_bf16<<<dim3((unsigned)blocks), dim3(256), 0, stream>>>(in, out, n);
    };
    cast(Wf[0], Wstk01,                 (long)D * D);
    cast(Wf[1], Wstk01 + (size_t)D * D, (long)D * D);
    for (int i = 0; i < 3; i++)
        cast(Wf[2 + i], Wstk234 + (size_t)i * D * D, (long)D * D);

    // pass 1: exact f32 row/col sums
    k_sums<true><<<dim3(NR / 64, NO / 64), dim3(256), 0, stream>>>(attn_sub, NR, invS, invTS);
    k_sums<true><<<dim3(NR / 64, NO / 64), dim3(256), 0, stream>>>(attn_obj, NR, invO, invTO);
    k_sums<false><<<dim3(NO / 64, NO / 64), dim3(256), 0, stream>>>(attn_self, NO, invSelf, nullptr);
    k_invscale<<<dim3((3 * NO + 255) / 256), dim3(256), 0, stream>>>(sums, 3 * NO, 1.f / 3.f);
    k_invscale<<<dim3((2 * NR + 255) / 256), dim3(256), 0, stream>>>(sums + 3 * NO, 2 * NR, 0.5f);

    // pass 2: scaled bf16 operands in concat layouts
    k_prep2<true><<<dim3(NR / 64, NO / 64), dim3(256), 0, stream>>>(
        attn_sub, NR, Aobj, Arel, invS, invTS);
    k_prep2<true><<<dim3(NR / 64, NO / 64), dim3(256), 0, stream>>>(
        attn_obj, NR, Aobj + 16384, Arel + 2048, invO, invTO);
    k_prep2<false><<<dim3(NO / 64, NO / 64), dim3(256), 0, stream>>>(
        attn_self, NO, Aobj + 32768, nullptr, invSelf, nullptr);

    for (int step = 0; step < 2; ++step) {
        cast(x_obj, xobj_bf, (long)NO * D);
        cast(x_rel, xrel_bf, (long)NR * D);

        // fcObj cols [0,32768): [f0|f1] = relu([W0;W1] @ xrel^T + b01)
        gemm256<2><<<dim3((2 * D / 256) * (NR / 256), 1, 1), dim3(512), 0, stream>>>(
            Wstk01, xrel_bf, 2 * D, NR, D, b01, fcObj, nullptr, KOBJ, NR / 256);
        // fcRel [f2|f3] + fcObj col [32768,34816) (f4) = relu([W2;W3;W4] @ xobj^T + b)
        gemm_bt_f234<<<dim3(3 * D / BM, NO / BN, 1), dim3(GT), 0, stream>>>(
            Wstk234, xobj_bf, 3 * D, NO, D, bstk, fcRel, fcObj);

        // x_obj += Aobj @ fcObj^T   (all three collects + scales folded)
        gemm256<1><<<dim3((NO / 256) * (D / 256), 1, 8), dim3(512), 0, stream>>>(
            Aobj, fcObj, NO, D, KOBJ, nullptr, nullptr, x_obj, D, D / 256);
        // x_rel += Arel @ fcRel^T   (both collects + scales folded)
        gemm256<1><<<dim3((NR / 256) * (D / 256), 1, 1), dim3(512), 0, stream>>>(
            Arel, fcRel, NR, D, KREL, nullptr, nullptr, x_rel, D, D / 256);
    }
}

// Round 5
// 1161.505 us; speedup vs baseline: 2.0814x; 1.0124x over previous
//
#include <hip/hip_runtime.h>
#include <hip/hip_bf16.h>

typedef __attribute__((ext_vector_type(4))) float  f32x4;
typedef __attribute__((ext_vector_type(8))) __bf16 bf16x8;
typedef __hip_bfloat16 bf16_t;

#define GT 256
#define BM 128
#define BN 128
#define BK 32

// problem constants
#define NOBJ 2048
#define NREL 16384
#define DIM  1024
#define KOBJ 34816   /* 16384 + 16384 + 2048 */
#define KREL 4096    /* 2048 + 2048 */

#define AS1Q __attribute__((address_space(1)))
#define AS3Q __attribute__((address_space(3)))

__device__ __forceinline__ void gload_lds16(const void* g, void* l) {
    __builtin_amdgcn_global_load_lds((AS1Q void*)const_cast<void*>(g),
                                     (AS3Q void*)l, 16, 0, 0);
}

#define MFMA_BF16 __builtin_amdgcn_mfma_f32_16x16x32_bf16

// ---------------------------------------------------------------------------
// 128x128 2-phase kernel — used once per step for the stacked obj-side FCs.
// C = A[M,K]*B[N,K]^T; epilogue routes rows to fcRel (f2,f3) / fcObj (f4).
// ---------------------------------------------------------------------------
__global__ __launch_bounds__(GT)
void gemm_bt_f234(const bf16_t* __restrict__ A, const bf16_t* __restrict__ B,
                  int M, int N, int K, const float* __restrict__ vecM,
                  bf16_t* __restrict__ fcRel, bf16_t* __restrict__ fcObj)
{
    __shared__ bf16_t sA[BM * BK];
    __shared__ bf16_t sB[BN * BK];

    const int tid  = threadIdx.x;
    const int lane = tid & 63;
    const int wid  = tid >> 6;
    const int wr = wid >> 1, wc = wid & 1;
    const int l15 = lane & 15, lk = lane >> 4;

    const long rowA0 = (long)blockIdx.x * BM;
    const long rowB0 = (long)blockIdx.y * BN;
    const long ldab  = (long)K * 2;

    const int c0 = tid, c1 = tid + GT;
    const int r0c = c0 >> 2, k0c = (c0 & 3) ^ ((r0c >> 1) & 3);
    const int r1c = c1 >> 2, k1c = (c1 & 3) ^ ((r1c >> 1) & 3);

    const char* gA0 = (const char*)A + (rowA0 + r0c) * ldab + k0c * 16;
    const char* gA1 = (const char*)A + (rowA0 + r1c) * ldab + k1c * 16;
    const char* gB0 = (const char*)B + (rowB0 + r0c) * ldab + k0c * 16;
    const char* gB1 = (const char*)B + (rowB0 + r1c) * ldab + k1c * 16;
    char* lA0 = (char*)sA + c0 * 16;
    char* lA1 = (char*)sA + c1 * 16;
    char* lB0 = (char*)sB + c0 * 16;
    char* lB1 = (char*)sB + c1 * 16;

    f32x4 acc[4][4];
    #pragma unroll
    for (int i = 0; i < 4; i++)
        #pragma unroll
        for (int j = 0; j < 4; j++) acc[i][j] = f32x4{0.f, 0.f, 0.f, 0.f};

    const int ktPer = K / BK;
    for (int kt = 0; kt < ktPer; ++kt) {
        const long kByte = (long)kt * (BK * 2);
        gload_lds16(gA0 + kByte, lA0);
        gload_lds16(gA1 + kByte, lA1);
        gload_lds16(gB0 + kByte, lB0);
        gload_lds16(gB1 + kByte, lB1);
        __syncthreads();

        bf16x8 af[4], bg[4];
        #pragma unroll
        for (int i = 0; i < 4; i++) {
            const int rr = wr * 64 + i * 16 + l15;
            const int kk = lk ^ ((rr >> 1) & 3);
            af[i] = *reinterpret_cast<const bf16x8*>((const char*)sA + rr * 64 + kk * 16);
        }
        #pragma unroll
        for (int j = 0; j < 4; j++) {
            const int rr = wc * 64 + j * 16 + l15;
            const int kk = lk ^ ((rr >> 1) & 3);
            bg[j] = *reinterpret_cast<const bf16x8*>((const char*)sB + rr * 64 + kk * 16);
        }
        #pragma unroll
        for (int i = 0; i < 4; i++)
            #pragma unroll
            for (int j = 0; j < 4; j++)
                acc[i][j] = MFMA_BF16(af[i], bg[j], acc[i][j], 0, 0, 0);
        __syncthreads();
    }

    #pragma unroll
    for (int i = 0; i < 4; i++) {
        const long mBase = rowA0 + wr * 64 + i * 16 + lk * 4;
        const f32x4 vm = *reinterpret_cast<const f32x4*>(&vecM[mBase]);
        #pragma unroll
        for (int r = 0; r < 4; r++) {
            const long m = mBase + r;
            #pragma unroll
            for (int j = 0; j < 4; j++) {
                const long n = rowB0 + wc * 64 + j * 16 + l15;
                const float v = fmaxf(acc[i][j][r] + vm[r], 0.f);
                const bf16_t o = __float2bfloat16(v);
                if (m < 1024)            fcRel[m * (long)KREL + n] = o;
                else if (m < 2048)       fcRel[(m - 1024) * (long)KREL + 2048 + n] = o;
                else                     fcObj[(m - 2048) * (long)KOBJ + 32768 + n] = o;
            }
        }
    }
}

// ---------------------------------------------------------------------------
// 256x256 8-phase kernel (T2+T3+T4+T5). 512 thr = 8 waves (2M x 4N).
// Quadrant phases (one NEW half-tile consumed per phase, >=2-phase vmcnt slack):
//   ph0: A-half0 x B-half0   (reads A kf0..3, B j0..1; stages A0(t+1))
//   ph1: A-half0 x B-half1   (reads B j2..3;          stages B0(t+1))
//   ph2: A-half1 x B-half0   (reads A kf4..7;         stages B1(t+1))
//   ph3: A-half1 x B-half1   (no reads;               stages A1(t+1))
// vmcnt(4) at ends of ph0/ph1/ph3 (never 0 in steady state).
// EPI 1: Cf[m*ldc+n] += acc (atomicAdd when gridDim.z>1; scales pre-folded)
// EPI 2: Cb[(m&1023)*ldc + (m>>10)*16384 + n] = bf16(relu(acc+vecM[m]))
// ---------------------------------------------------------------------------
template<int EPI>
__global__ __launch_bounds__(512, 2)
void gemm256(const bf16_t* __restrict__ A, const bf16_t* __restrict__ B,
             int M, int N, int K, const float* __restrict__ vecM,
             bf16_t* __restrict__ Cb, float* __restrict__ Cf,
             int ldc, int Ntiles)
{
    __shared__ __align__(16) char lds[131072];

    const int tid  = threadIdx.x;
    const int lane = tid & 63;
    const int wid  = tid >> 6;
    const int wr = wid >> 2, wc = wid & 3;
    const int l15 = lane & 15, lk = lane >> 4;

    const int nwg = gridDim.x;
    const int cpx = nwg >> 3;
    const int bid = blockIdx.x;
    const int swz = (bid & 7) * cpx + (bid >> 3);
    const int tm = swz / Ntiles, tn = swz % Ntiles;
    const long rowM0 = (long)tm * 256;
    const long rowN0 = (long)tn * 256;
    const long ld = (long)K * 2;

    const int nz = gridDim.z;
    const int NT = (K >> 6) / nz;
    const long kb0 = (long)NT * blockIdx.z * 128;

    const int rl = tid >> 3;
    const int lc = (tid & 7) ^ (rl & 7);
    const char* gA0 = (const char*)A + (rowM0 + rl) * ld + kb0 + lc * 16;
    const char* gB0 = (const char*)B + (rowN0 + rl) * ld + kb0 + lc * 16;

    auto stage = [&](int buf, int isB, int h, int t) {
        const char* g = (isB ? gB0 : gA0) + (long)h * 128 * ld + (long)t * 128;
        char* l = (char*)lds + buf * 65536 + isB * 32768 + h * 16384 + tid * 16;
        gload_lds16(g, l);
        gload_lds16(g + 64 * ld, l + 8192);
    };

    const int xo0 = ((0 + lk) ^ (l15 & 7)) * 16;
    const int xo1 = ((4 + lk) ^ (l15 & 7)) * 16;
    const int baseA = (wr * 16 + l15) * 128;
    const int baseB = 32768 + (wc * 16 + l15) * 128;

    f32x4 acc[8][4];
    #pragma unroll
    for (int i = 0; i < 8; i++)
        #pragma unroll
        for (int j = 0; j < 4; j++) acc[i][j] = f32x4{0.f, 0.f, 0.f, 0.f};

    // prologue: stage tile0 {A0,B0,B1,A1}; allow B1,A1 to stay in flight
    stage(0, 0, 0, 0); stage(0, 1, 0, 0); stage(0, 1, 1, 0); stage(0, 0, 1, 0);
    asm volatile("s_waitcnt vmcnt(4)" ::: "memory");
    __builtin_amdgcn_sched_barrier(0);
    __builtin_amdgcn_s_barrier();

    bf16x8 a[4][2], b0[2][2], b1[2][2];
    for (int t = 0; t < NT; ++t) {
        const int cur = t & 1;
        const int nxt = cur ^ 1;
        const bool pf = (t + 1) < NT;
        const char* lcur = (const char*)lds + (cur << 16);

        // ---------------- phase 0: A-half0 x B-half0 ----------------
        #pragma unroll
        for (int kf = 0; kf < 4; kf++) {
            a[kf][0] = *(const bf16x8*)(lcur + baseA + kf * 4096 + xo0);
            a[kf][1] = *(const bf16x8*)(lcur + baseA + kf * 4096 + xo1);
        }
        #pragma unroll
        for (int j = 0; j < 2; j++) {
            b0[j][0] = *(const bf16x8*)(lcur + baseB + j * 8192 + xo0);
            b0[j][1] = *(const bf16x8*)(lcur + baseB + j * 8192 + xo1);
        }
        if (pf) stage(nxt, 0, 0, t + 1);
        __builtin_amdgcn_s_barrier();
        asm volatile("s_waitcnt lgkmcnt(0)" ::: "memory");
        __builtin_amdgcn_sched_barrier(0);
        __builtin_amdgcn_s_setprio(1);
        #pragma unroll
        for (int j = 0; j < 2; j++)
            #pragma unroll
            for (int kf = 0; kf < 4; kf++) {
                acc[kf][j] = MFMA_BF16(a[kf][0], b0[j][0], acc[kf][j], 0, 0, 0);
                acc[kf][j] = MFMA_BF16(a[kf][1], b0[j][1], acc[kf][j], 0, 0, 0);
            }
        __builtin_amdgcn_s_setprio(0);
        if (pf) { asm volatile("s_waitcnt vmcnt(4)" ::: "memory"); }
        else    { asm volatile("s_waitcnt vmcnt(2)" ::: "memory"); }
        __builtin_amdgcn_sched_barrier(0);
        __builtin_amdgcn_s_barrier();

        // ---------------- phase 1: A-half0 x B-half1 ----------------
        #pragma unroll
        for (int j = 0; j < 2; j++) {
            b1[j][0] = *(const bf16x8*)(lcur + baseB + (2 + j) * 8192 + xo0);
            b1[j][1] = *(const bf16x8*)(lcur + baseB + (2 + j) * 8192 + xo1);
        }
        if (pf) stage(nxt, 1, 0, t + 1);
        __builtin_amdgcn_s_barrier();
        asm volatile("s_waitcnt lgkmcnt(0)" ::: "memory");
        __builtin_amdgcn_sched_barrier(0);
        __builtin_amdgcn_s_setprio(1);
        #pragma unroll
        for (int j = 0; j < 2; j++)
            #pragma unroll
            for (int kf = 0; kf < 4; kf++) {
                acc[kf][2 + j] = MFMA_BF16(a[kf][0], b1[j][0], acc[kf][2 + j], 0, 0, 0);
                acc[kf][2 + j] = MFMA_BF16(a[kf][1], b1[j][1], acc[kf][2 + j], 0, 0, 0);
            }
        __builtin_amdgcn_s_setprio(0);
        if (pf) { asm volatile("s_waitcnt vmcnt(4)" ::: "memory"); }
        else    { asm volatile("s_waitcnt vmcnt(0)" ::: "memory"); }
        __builtin_amdgcn_sched_barrier(0);
        __builtin_amdgcn_s_barrier();

        // ---------------- phase 2: A-half1 x B-half0 ----------------
        #pragma unroll
        for (int kf = 0; kf < 4; kf++) {
            a[kf][0] = *(const bf16x8*)(lcur + baseA + (4 + kf) * 4096 + xo0);
            a[kf][1] = *(const bf16x8*)(lcur + baseA + (4 + kf) * 4096 + xo1);
        }
        if (pf) stage(nxt, 1, 1, t + 1);
        __builtin_amdgcn_s_barrier();
        asm volatile("s_waitcnt lgkmcnt(0)" ::: "memory");
        __builtin_amdgcn_sched_barrier(0);
        __builtin_amdgcn_s_setprio(1);
        #pragma unroll
        for (int j = 0; j < 2; j++)
            #pragma unroll
            for (int kf = 0; kf < 4; kf++) {
                acc[4 + kf][j] = MFMA_BF16(a[kf][0], b0[j][0], acc[4 + kf][j], 0, 0, 0);
                acc[4 + kf][j] = MFMA_BF16(a[kf][1], b0[j][1], acc[4 + kf][j], 0, 0, 0);
            }
        __builtin_amdgcn_s_setprio(0);
        __builtin_amdgcn_s_barrier();

        // ---------------- phase 3: A-half1 x B-half1 ----------------
        if (pf) stage(nxt, 0, 1, t + 1);
        __builtin_amdgcn_s_barrier();
        __builtin_amdgcn_s_setprio(1);
        #pragma unroll
        for (int j = 0; j < 2; j++)
            #pragma unroll
            for (int kf = 0; kf < 4; kf++) {
                acc[4 + kf][2 + j] = MFMA_BF16(a[kf][0], b1[j][0], acc[4 + kf][2 + j], 0, 0, 0);
                acc[4 + kf][2 + j] = MFMA_BF16(a[kf][1], b1[j][1], acc[4 + kf][2 + j], 0, 0, 0);
            }
        __builtin_amdgcn_s_setprio(0);
        if (pf) { asm volatile("s_waitcnt vmcnt(4)" ::: "memory"); }
        __builtin_amdgcn_sched_barrier(0);
        __builtin_amdgcn_s_barrier();
    }

    #pragma unroll
    for (int kf = 0; kf < 8; kf++) {
        const long m0 = rowM0 + wr * 16 + kf * 32 + lk * 4;
        f32x4 vm = f32x4{0.f, 0.f, 0.f, 0.f};
        if constexpr (EPI == 2) vm = *reinterpret_cast<const f32x4*>(vecM + m0);
        #pragma unroll
        for (int r = 0; r < 4; r++) {
            const long m = m0 + r;
            #pragma unroll
            for (int j = 0; j < 4; j++) {
                const long n = rowN0 + wc * 16 + j * 64 + l15;
                const float v = acc[kf][j][r];
                if constexpr (EPI == 1) {
                    if (nz == 1) Cf[m * (long)ldc + n] += v;
                    else atomicAdd(&Cf[m * (long)ldc + n], v);
                } else {
                    const float o = fmaxf(v + vm[r], 0.f);
                    Cb[(m & 1023) * (long)ldc + (m >> 10) * 16384 + n] = __float2bfloat16(o);
                }
            }
        }
    }
}

__global__ __launch_bounds__(256)
void k_cast_bf16(const float* __restrict__ in, bf16_t* __restrict__ out, long n)
{
    const long stride = (long)gridDim.x * blockDim.x;
    for (long i = (long)blockIdx.x * blockDim.x + threadIdx.x; i * 4 < n; i += stride) {
        f32x4 v = *reinterpret_cast<const f32x4*>(in + i * 4);
        union { bf16_t h[4]; ushort4 u; } o;
        o.h[0] = __float2bfloat16(v[0]); o.h[1] = __float2bfloat16(v[1]);
        o.h[2] = __float2bfloat16(v[2]); o.h[3] = __float2bfloat16(v[3]);
        *reinterpret_cast<ushort4*>(out + i * 4) = o.u;
    }
}

// Pass 1: row-sum (+ optional col-sum) partials of f32 attn via atomics.
template<bool COLS>
__global__ __launch_bounds__(256)
void k_sums(const float* __restrict__ in, int C,
            float* __restrict__ rowsum, float* __restrict__ colsum)
{
    __shared__ float cpart[16][64];
    __shared__ float rpart[64][17];
    const int tid = threadIdx.x;
    const int tx  = tid & 15;
    const int ty  = tid >> 4;
    const long c0 = (long)blockIdx.x * 64;
    const long r0 = (long)blockIdx.y * 64;

    float cs0 = 0.f, cs1 = 0.f, cs2 = 0.f, cs3 = 0.f;
    #pragma unroll
    for (int i = 0; i < 4; i++) {
        const int r = i * 16 + ty;
        const f32x4 v = *reinterpret_cast<const f32x4*>(&in[(r0 + r) * (long)C + c0 + tx * 4]);
        rpart[r][tx] = v[0] + v[1] + v[2] + v[3];
        cs0 += v[0]; cs1 += v[1]; cs2 += v[2]; cs3 += v[3];
    }
    if (COLS) {
        cpart[ty][tx * 4 + 0] = cs0;
        cpart[ty][tx * 4 + 1] = cs1;
        cpart[ty][tx * 4 + 2] = cs2;
        cpart[ty][tx * 4 + 3] = cs3;
    }
    __syncthreads();
    if (tid < 64) {
        float rs = 0.f;
        #pragma unroll
        for (int k = 0; k < 16; k++) rs += rpart[tid][k];
        atomicAdd(&rowsum[r0 + tid], rs);
        if (COLS) {
            float cs = 0.f;
            #pragma unroll
            for (int k = 0; k < 16; k++) cs += cpart[k][tid];
            atomicAdd(&colsum[c0 + tid], cs);
        }
    }
}

__global__ __launch_bounds__(256)
void k_invscale(float* __restrict__ s, int n, float c)
{
    const int i = blockIdx.x * 256 + threadIdx.x;
    if (i < n) s[i] = c / (s[i] + 1e-7f);
}

// Pass 2: scaled bf16 write into concat layouts.
template<bool TRANS>
__global__ __launch_bounds__(256)
void k_prep2(const float* __restrict__ in, int C,
             bf16_t* __restrict__ Aobj, bf16_t* __restrict__ Arel,
             const float* __restrict__ invRow, const float* __restrict__ invCol)
{
    __shared__ float tile[64][65];
    const int tid = threadIdx.x;
    const int tx  = tid & 15;
    const int ty  = tid >> 4;
    const long c0 = (long)blockIdx.x * 64;
    const long r0 = (long)blockIdx.y * 64;

    #pragma unroll
    for (int i = 0; i < 4; i++) {
        const int r = i * 16 + ty;
        const f32x4 v = *reinterpret_cast<const f32x4*>(&in[(r0 + r) * (long)C + c0 + tx * 4]);
        const float sc = invRow[r0 + r];
        union { bf16_t h[4]; ushort4 u; } o;
        o.h[0] = __float2bfloat16(v[0] * sc); o.h[1] = __float2bfloat16(v[1] * sc);
        o.h[2] = __float2bfloat16(v[2] * sc); o.h[3] = __float2bfloat16(v[3] * sc);
        *reinterpret_cast<ushort4*>(&Aobj[(r0 + r) * (long)KOBJ + c0 + tx * 4]) = o.u;
        if (TRANS) *reinterpret_cast<f32x4*>(&tile[r][tx * 4]) = v;
    }
    if (TRANS) {
        __syncthreads();
        const int rr = tid & 63;
        const int cg = tid >> 6;
        #pragma unroll
        for (int i = 0; i < 16; i++) {
            const int c = cg * 16 + i;
            const float sc = invCol[c0 + c];
            Arel[(c0 + c) * (long)KREL + r0 + rr] = __float2bfloat16(tile[rr][c] * sc);
        }
    }
}

extern "C" void kernel_launch(void* const* d_in, const int* in_sizes, int n_in,
                              void* d_out, int out_size, void* d_ws, size_t ws_size,
                              hipStream_t stream)
{
    if (n_in < 15) return;
    const float* obj_feats = (const float*)d_in[0];
    const float* rel_feats = (const float*)d_in[1];
    const float* attn_sub  = (const float*)d_in[2];
    const float* attn_obj  = (const float*)d_in[3];
    const float* attn_self = (const float*)d_in[4];
    const float* Wf[5] = { (const float*)d_in[5], (const float*)d_in[7],
                           (const float*)d_in[9], (const float*)d_in[11], (const float*)d_in[13] };
    const float* Bf[5] = { (const float*)d_in[6], (const float*)d_in[8],
                           (const float*)d_in[10], (const float*)d_in[12], (const float*)d_in[14] };

    const int NO = NOBJ, NR = NREL, D = DIM;

    char* w = (char*)d_ws;
    auto take = [&](size_t bytes) { char* p = w; w += bytes; return p; };
    bf16_t* Aobj    = (bf16_t*)take((size_t)NO * KOBJ * 2);     // [2048][34816]
    bf16_t* Arel    = (bf16_t*)take((size_t)NR * KREL * 2);     // [16384][4096]
    bf16_t* fcObj   = (bf16_t*)take((size_t)D * KOBJ * 2);      // [1024][34816]
    bf16_t* fcRel   = (bf16_t*)take((size_t)D * KREL * 2);      // [1024][4096]
    bf16_t* xrel_bf = (bf16_t*)take((size_t)NR * D * 2);
    bf16_t* xobj_bf = (bf16_t*)take((size_t)NO * D * 2);
    bf16_t* Wstk01  = (bf16_t*)take((size_t)2 * D * D * 2);     // [W0;W1]
    bf16_t* Wstk234 = (bf16_t*)take((size_t)3 * D * D * 2);     // [W2;W3;W4]
    float*  b01     = (float*)take((size_t)2 * D * 4);
    float*  bstk    = (float*)take((size_t)3 * D * 4);
    float*  sums    = (float*)take((size_t)(3 * NO + 2 * NR) * 4);
    float* invS     = sums;            // 1/(3(rowsum_AS+eps))
    float* invO     = sums + NO;
    float* invSelf  = sums + 2 * NO;
    float* invTS    = sums + 3 * NO;   // 0.5/(colsum_AS+eps)
    float* invTO    = sums + 3 * NO + NR;
    if ((size_t)(w - (char*)d_ws) > ws_size) return;   // ws too small: fail loudly

    float* x_obj = (float*)d_out;
    float* x_rel = x_obj + (size_t)NO * D;

    hipMemcpyAsync(x_obj, obj_feats, (size_t)NO * D * 4, hipMemcpyDeviceToDevice, stream);
    hipMemcpyAsync(x_rel, rel_feats, (size_t)NR * D * 4, hipMemcpyDeviceToDevice, stream);
    hipMemcpyAsync(b01,     Bf[0], (size_t)D * 4, hipMemcpyDeviceToDevice, stream);
    hipMemcpyAsync(b01 + D, Bf[1], (size_t)D * 4, hipMemcpyDeviceToDevice, stream);
    for (int i = 0; i < 3; i++)
        hipMemcpyAsync(bstk + i * D, Bf[2 + i], (size_t)D * 4, hipMemcpyDeviceToDevice, stream);
    hipMemsetAsync(sums, 0, (size_t)(3 * NO + 2 * NR) * 4, stream);

    auto cast = [&](const float* in, bf16_t* out, long n) {
        long blocks = (n / 4 + 255) / 256; if (blocks > 4096) blocks = 4096;
        k_cast_bf16<<<dim3((unsigned)blocks), dim3(256), 0, stream>>>(in, out, n);
    };
    cast(Wf[0], Wstk01,                 (long)D * D);
    cast(Wf[1], Wstk01 + (size_t)D * D, (long)D * D);
    for (int i = 0; i < 3; i++)
        cast(Wf[2 + i], Wstk234 + (size_t)i * D * D, (long)D * D);

    // pass 1: exact f32 row/col sums
    k_sums<true><<<dim3(NR / 64, NO / 64), dim3(256), 0, stream>>>(attn_sub, NR, invS, invTS);
    k_sums<true><<<dim3(NR / 64, NO / 64), dim3(256), 0, stream>>>(attn_obj, NR, invO, invTO);
    k_sums<false><<<dim3(NO / 64, NO / 64), dim3(256), 0, stream>>>(attn_self, NO, invSelf, nullptr);
    k_invscale<<<dim3((3 * NO + 255) / 256), dim3(256), 0, stream>>>(sums, 3 * NO, 1.f / 3.f);
    k_invscale<<<dim3((2 * NR + 255) / 256), dim3(256), 0, stream>>>(sums + 3 * NO, 2 * NR, 0.5f);

    // pass 2: scaled bf16 operands in concat layouts
    k_prep2<true><<<dim3(NR / 64, NO / 64), dim3(256), 0, stream>>>(
        attn_sub, NR, Aobj, Arel, invS, invTS);
    k_prep2<true><<<dim3(NR / 64, NO / 64), dim3(256), 0, stream>>>(
        attn_obj, NR, Aobj + 16384, Arel + 2048, invO, invTO);
    k_prep2<false><<<dim3(NO / 64, NO / 64), dim3(256), 0, stream>>>(
        attn_self, NO, Aobj + 32768, nullptr, invSelf, nullptr);

    for (int step = 0; step < 2; ++step) {
        cast(x_obj, xobj_bf, (long)NO * D);
        cast(x_rel, xrel_bf, (long)NR * D);

        // fcObj cols [0,32768): [f0|f1] = relu([W0;W1] @ xrel^T + b01)
        gemm256<2><<<dim3((2 * D / 256) * (NR / 256), 1, 1), dim3(512), 0, stream>>>(
            Wstk01, xrel_bf, 2 * D, NR, D, b01, fcObj, nullptr, KOBJ, NR / 256);
        // fcRel [f2|f3] + fcObj col [32768,34816) (f4) = relu([W2;W3;W4] @ xobj^T + b)
        gemm_bt_f234<<<dim3(3 * D / BM, NO / BN, 1), dim3(GT), 0, stream>>>(
            Wstk234, xobj_bf, 3 * D, NO, D, bstk, fcRel, fcObj);

        // x_obj += Aobj @ fcObj^T   (all three collects + scales folded)
        gemm256<1><<<dim3((NO / 256) * (D / 256), 1, 8), dim3(512), 0, stream>>>(
            Aobj, fcObj, NO, D, KOBJ, nullptr, nullptr, x_obj, D, D / 256);
        // x_rel += Arel @ fcRel^T   (both collects + scales folded)
        gemm256<1><<<dim3((NR / 256) * (D / 256), 1, 1), dim3(512), 0, stream>>>(
            Arel, fcRel, NR, D, KREL, nullptr, nullptr, x_rel, D, D / 256);
    }
}

// Round 6
// 952.193 us; speedup vs baseline: 2.5389x; 1.2198x over previous
//
#include <hip/hip_runtime.h>
#include <hip/hip_bf16.h>

typedef __attribute__((ext_vector_type(4))) float  f32x4;
typedef __attribute__((ext_vector_type(8))) __bf16 bf16x8;
typedef __attribute__((ext_vector_type(4))) int    i32x4;
typedef __attribute__((ext_vector_type(8))) int    i32x8;
typedef __hip_bfloat16 bf16_t;

#define GT 256
#define BM 128
#define BN 128
#define BK 32

// problem constants
#define NOBJ 2048
#define NREL 16384
#define DIM  1024
#define KOBJ 34816   /* 16384 + 16384 + 2048 */
#define KREL 4096    /* 2048 + 2048 */

#define AS1Q __attribute__((address_space(1)))
#define AS3Q __attribute__((address_space(3)))

__device__ __forceinline__ void gload_lds16(const void* g, void* l) {
    __builtin_amdgcn_global_load_lds((AS1Q void*)const_cast<void*>(g),
                                     (AS3Q void*)l, 16, 0, 0);
}

#define MFMA_BF16 __builtin_amdgcn_mfma_f32_16x16x32_bf16
// all-ones (E8M0 = 127) block scales: plain fp8 matmul at MX rate
#define MFMA_F8(ACC, Af, Bf) \
    ACC = __builtin_amdgcn_mfma_scale_f32_16x16x128_f8f6f4( \
        Af, Bf, ACC, 0, 0, 0, 0x7F7F7F7F, 0, 0x7F7F7F7F)

__device__ __forceinline__ unsigned char fp8_byte(float x) {
    return (unsigned char)(__builtin_amdgcn_cvt_pk_fp8_f32(x, x, 0, false) & 0xFF);
}
__device__ __forceinline__ unsigned pk4_fp8(float a, float b, float c, float d) {
    int v = __builtin_amdgcn_cvt_pk_fp8_f32(a, b, 0, false);
    v = __builtin_amdgcn_cvt_pk_fp8_f32(c, d, v, true);
    return (unsigned)v;
}

// ---------------------------------------------------------------------------
// 128x128 2-phase bf16 kernel — stacked obj-side FCs; fp8 outputs routed to
// fcRel8 (f2,f3) / fcObj8 (f4).
// ---------------------------------------------------------------------------
__global__ __launch_bounds__(GT)
void gemm_bt_f234(const bf16_t* __restrict__ A, const bf16_t* __restrict__ B,
                  int M, int N, int K, const float* __restrict__ vecM,
                  unsigned char* __restrict__ fcRel8, unsigned char* __restrict__ fcObj8)
{
    __shared__ bf16_t sA[BM * BK];
    __shared__ bf16_t sB[BN * BK];

    const int tid  = threadIdx.x;
    const int lane = tid & 63;
    const int wid  = tid >> 6;
    const int wr = wid >> 1, wc = wid & 1;
    const int l15 = lane & 15, lk = lane >> 4;

    const long rowA0 = (long)blockIdx.x * BM;
    const long rowB0 = (long)blockIdx.y * BN;
    const long ldab  = (long)K * 2;

    const int c0 = tid, c1 = tid + GT;
    const int r0c = c0 >> 2, k0c = (c0 & 3) ^ ((r0c >> 1) & 3);
    const int r1c = c1 >> 2, k1c = (c1 & 3) ^ ((r1c >> 1) & 3);

    const char* gA0 = (const char*)A + (rowA0 + r0c) * ldab + k0c * 16;
    const char* gA1 = (const char*)A + (rowA0 + r1c) * ldab + k1c * 16;
    const char* gB0 = (const char*)B + (rowB0 + r0c) * ldab + k0c * 16;
    const char* gB1 = (const char*)B + (rowB0 + r1c) * ldab + k1c * 16;
    char* lA0 = (char*)sA + c0 * 16;
    char* lA1 = (char*)sA + c1 * 16;
    char* lB0 = (char*)sB + c0 * 16;
    char* lB1 = (char*)sB + c1 * 16;

    f32x4 acc[4][4];
    #pragma unroll
    for (int i = 0; i < 4; i++)
        #pragma unroll
        for (int j = 0; j < 4; j++) acc[i][j] = f32x4{0.f, 0.f, 0.f, 0.f};

    const int ktPer = K / BK;
    for (int kt = 0; kt < ktPer; ++kt) {
        const long kByte = (long)kt * (BK * 2);
        gload_lds16(gA0 + kByte, lA0);
        gload_lds16(gA1 + kByte, lA1);
        gload_lds16(gB0 + kByte, lB0);
        gload_lds16(gB1 + kByte, lB1);
        __syncthreads();

        bf16x8 af[4], bg[4];
        #pragma unroll
        for (int i = 0; i < 4; i++) {
            const int rr = wr * 64 + i * 16 + l15;
            const int kk = lk ^ ((rr >> 1) & 3);
            af[i] = *reinterpret_cast<const bf16x8*>((const char*)sA + rr * 64 + kk * 16);
        }
        #pragma unroll
        for (int j = 0; j < 4; j++) {
            const int rr = wc * 64 + j * 16 + l15;
            const int kk = lk ^ ((rr >> 1) & 3);
            bg[j] = *reinterpret_cast<const bf16x8*>((const char*)sB + rr * 64 + kk * 16);
        }
        #pragma unroll
        for (int i = 0; i < 4; i++)
            #pragma unroll
            for (int j = 0; j < 4; j++)
                acc[i][j] = MFMA_BF16(af[i], bg[j], acc[i][j], 0, 0, 0);
        __syncthreads();
    }

    #pragma unroll
    for (int i = 0; i < 4; i++) {
        const long mBase = rowA0 + wr * 64 + i * 16 + lk * 4;
        const f32x4 vm = *reinterpret_cast<const f32x4*>(&vecM[mBase]);
        #pragma unroll
        for (int r = 0; r < 4; r++) {
            const long m = mBase + r;
            #pragma unroll
            for (int j = 0; j < 4; j++) {
                const long n = rowB0 + wc * 64 + j * 16 + l15;
                const float v = fmaxf(acc[i][j][r] + vm[r], 0.f);
                const unsigned char o = fp8_byte(v);
                if (m < 1024)            fcRel8[m * (long)KREL + n] = o;
                else if (m < 2048)       fcRel8[(m - 1024) * (long)KREL + 2048 + n] = o;
                else                     fcObj8[(m - 2048) * (long)KOBJ + 32768 + n] = o;
            }
        }
    }
}

// ---------------------------------------------------------------------------
// 256x256 8-phase bf16 kernel — fc01 only now (EPI 2): fp8 output routed into
// fcObj8 column slices.
// ---------------------------------------------------------------------------
__global__ __launch_bounds__(512, 2)
void gemm256fc(const bf16_t* __restrict__ A, const bf16_t* __restrict__ B,
               int M, int N, int K, const float* __restrict__ vecM,
               unsigned char* __restrict__ Cb8, int ldc, int Ntiles)
{
    __shared__ __align__(16) char lds[131072];

    const int tid  = threadIdx.x;
    const int lane = tid & 63;
    const int wid  = tid >> 6;
    const int wr = wid >> 2, wc = wid & 3;
    const int l15 = lane & 15, lk = lane >> 4;

    const int nwg = gridDim.x;
    const int cpx = nwg >> 3;
    const int bid = blockIdx.x;
    const int swz = (bid & 7) * cpx + (bid >> 3);
    const int tm = swz / Ntiles, tn = swz % Ntiles;
    const long rowM0 = (long)tm * 256;
    const long rowN0 = (long)tn * 256;
    const long ld = (long)K * 2;

    const int NT = K >> 6;

    const int rl = tid >> 3;
    const int lc = (tid & 7) ^ (rl & 7);
    const char* gA0 = (const char*)A + (rowM0 + rl) * ld + lc * 16;
    const char* gB0 = (const char*)B + (rowN0 + rl) * ld + lc * 16;

    auto stage = [&](int buf, int isB, int h, int t) {
        const char* g = (isB ? gB0 : gA0) + (long)h * 128 * ld + (long)t * 128;
        char* l = (char*)lds + buf * 65536 + isB * 32768 + h * 16384 + tid * 16;
        gload_lds16(g, l);
        gload_lds16(g + 64 * ld, l + 8192);
    };

    const int xo0 = ((0 + lk) ^ (l15 & 7)) * 16;
    const int xo1 = ((4 + lk) ^ (l15 & 7)) * 16;
    const int baseA = (wr * 16 + l15) * 128;
    const int baseB = 32768 + (wc * 16 + l15) * 128;

    f32x4 acc[8][4];
    #pragma unroll
    for (int i = 0; i < 8; i++)
        #pragma unroll
        for (int j = 0; j < 4; j++) acc[i][j] = f32x4{0.f, 0.f, 0.f, 0.f};

    stage(0, 0, 0, 0); stage(0, 1, 0, 0); stage(0, 1, 1, 0); stage(0, 0, 1, 0);
    asm volatile("s_waitcnt vmcnt(4)" ::: "memory");
    __builtin_amdgcn_sched_barrier(0);
    __builtin_amdgcn_s_barrier();

    bf16x8 a[4][2], b0[2][2], b1[2][2];
    for (int t = 0; t < NT; ++t) {
        const int cur = t & 1;
        const int nxt = cur ^ 1;
        const bool pf = (t + 1) < NT;
        const char* lcur = (const char*)lds + (cur << 16);

        #pragma unroll
        for (int kf = 0; kf < 4; kf++) {
            a[kf][0] = *(const bf16x8*)(lcur + baseA + kf * 4096 + xo0);
            a[kf][1] = *(const bf16x8*)(lcur + baseA + kf * 4096 + xo1);
        }
        #pragma unroll
        for (int j = 0; j < 2; j++) {
            b0[j][0] = *(const bf16x8*)(lcur + baseB + j * 8192 + xo0);
            b0[j][1] = *(const bf16x8*)(lcur + baseB + j * 8192 + xo1);
        }
        if (pf) stage(nxt, 0, 0, t + 1);
        __builtin_amdgcn_s_barrier();
        asm volatile("s_waitcnt lgkmcnt(0)" ::: "memory");
        __builtin_amdgcn_sched_barrier(0);
        __builtin_amdgcn_s_setprio(1);
        #pragma unroll
        for (int j = 0; j < 2; j++)
            #pragma unroll
            for (int kf = 0; kf < 4; kf++) {
                acc[kf][j] = MFMA_BF16(a[kf][0], b0[j][0], acc[kf][j], 0, 0, 0);
                acc[kf][j] = MFMA_BF16(a[kf][1], b0[j][1], acc[kf][j], 0, 0, 0);
            }
        __builtin_amdgcn_s_setprio(0);
        if (pf) { asm volatile("s_waitcnt vmcnt(4)" ::: "memory"); }
        else    { asm volatile("s_waitcnt vmcnt(2)" ::: "memory"); }
        __builtin_amdgcn_sched_barrier(0);
        __builtin_amdgcn_s_barrier();

        #pragma unroll
        for (int j = 0; j < 2; j++) {
            b1[j][0] = *(const bf16x8*)(lcur + baseB + (2 + j) * 8192 + xo0);
            b1[j][1] = *(const bf16x8*)(lcur + baseB + (2 + j) * 8192 + xo1);
        }
        if (pf) stage(nxt, 1, 0, t + 1);
        __builtin_amdgcn_s_barrier();
        asm volatile("s_waitcnt lgkmcnt(0)" ::: "memory");
        __builtin_amdgcn_sched_barrier(0);
        __builtin_amdgcn_s_setprio(1);
        #pragma unroll
        for (int j = 0; j < 2; j++)
            #pragma unroll
            for (int kf = 0; kf < 4; kf++) {
                acc[kf][2 + j] = MFMA_BF16(a[kf][0], b1[j][0], acc[kf][2 + j], 0, 0, 0);
                acc[kf][2 + j] = MFMA_BF16(a[kf][1], b1[j][1], acc[kf][2 + j], 0, 0, 0);
            }
        __builtin_amdgcn_s_setprio(0);
        if (pf) { asm volatile("s_waitcnt vmcnt(4)" ::: "memory"); }
        else    { asm volatile("s_waitcnt vmcnt(0)" ::: "memory"); }
        __builtin_amdgcn_sched_barrier(0);
        __builtin_amdgcn_s_barrier();

        #pragma unroll
        for (int kf = 0; kf < 4; kf++) {
            a[kf][0] = *(const bf16x8*)(lcur + baseA + (4 + kf) * 4096 + xo0);
            a[kf][1] = *(const bf16x8*)(lcur + baseA + (4 + kf) * 4096 + xo1);
        }
        if (pf) stage(nxt, 1, 1, t + 1);
        __builtin_amdgcn_s_barrier();
        asm volatile("s_waitcnt lgkmcnt(0)" ::: "memory");
        __builtin_amdgcn_sched_barrier(0);
        __builtin_amdgcn_s_setprio(1);
        #pragma unroll
        for (int j = 0; j < 2; j++)
            #pragma unroll
            for (int kf = 0; kf < 4; kf++) {
                acc[4 + kf][j] = MFMA_BF16(a[kf][0], b0[j][0], acc[4 + kf][j], 0, 0, 0);
                acc[4 + kf][j] = MFMA_BF16(a[kf][1], b0[j][1], acc[4 + kf][j], 0, 0, 0);
            }
        __builtin_amdgcn_s_setprio(0);
        __builtin_amdgcn_s_barrier();

        if (pf) stage(nxt, 0, 1, t + 1);
        __builtin_amdgcn_s_barrier();
        __builtin_amdgcn_s_setprio(1);
        #pragma unroll
        for (int j = 0; j < 2; j++)
            #pragma unroll
            for (int kf = 0; kf < 4; kf++) {
                acc[4 + kf][2 + j] = MFMA_BF16(a[kf][0], b1[j][0], acc[4 + kf][2 + j], 0, 0, 0);
                acc[4 + kf][2 + j] = MFMA_BF16(a[kf][1], b1[j][1], acc[4 + kf][2 + j], 0, 0, 0);
            }
        __builtin_amdgcn_s_setprio(0);
        if (pf) { asm volatile("s_waitcnt vmcnt(4)" ::: "memory"); }
        __builtin_amdgcn_sched_barrier(0);
        __builtin_amdgcn_s_barrier();
    }

    #pragma unroll
    for (int kf = 0; kf < 8; kf++) {
        const long m0 = rowM0 + wr * 16 + kf * 32 + lk * 4;
        const f32x4 vm = *reinterpret_cast<const f32x4*>(vecM + m0);
        #pragma unroll
        for (int r = 0; r < 4; r++) {
            const long m = m0 + r;
            #pragma unroll
            for (int j = 0; j < 4; j++) {
                const long n = rowN0 + wc * 16 + j * 64 + l15;
                const float o = fmaxf(acc[kf][j][r] + vm[r], 0.f);
                Cb8[(m & 1023) * (long)ldc + (m >> 10) * 16384 + n] = fp8_byte(o);
            }
        }
    }
}

// ---------------------------------------------------------------------------
// 256x256 MX-fp8 collect kernel (K-tile = 128 bytes; scales = 1.0).
// Byte-identical staging/swizzle/vmcnt skeleton to the bf16 kernel.
// Cf[m*ldc+n] += acc * scale   (atomicAdd when gridDim.z>1)
// ---------------------------------------------------------------------------
__global__ __launch_bounds__(512, 2)
void gemm256f8(const unsigned char* __restrict__ A, const unsigned char* __restrict__ B,
               int M, int N, int K, float* __restrict__ Cf, float scale,
               int ldc, int Ntiles)
{
    __shared__ __align__(16) char lds[131072];

    const int tid  = threadIdx.x;
    const int lane = tid & 63;
    const int wid  = tid >> 6;
    const int wr = wid >> 2, wc = wid & 3;
    const int l15 = lane & 15, lk = lane >> 4;

    const int nwg = gridDim.x;
    const int cpx = nwg >> 3;
    const int bid = blockIdx.x;
    const int swz = (bid & 7) * cpx + (bid >> 3);
    const int tm = swz / Ntiles, tn = swz % Ntiles;
    const long rowM0 = (long)tm * 256;
    const long rowN0 = (long)tn * 256;
    const long ld = (long)K;            // bytes per row

    const int nz = gridDim.z;
    const int NT = (K >> 7) / nz;       // K-tiles of 128 bytes
    const long kb0 = (long)NT * blockIdx.z * 128;

    const int rl = tid >> 3;
    const int lc = (tid & 7) ^ (rl & 7);
    const char* gA0 = (const char*)A + (rowM0 + rl) * ld + kb0 + lc * 16;
    const char* gB0 = (const char*)B + (rowN0 + rl) * ld + kb0 + lc * 16;

    auto stage = [&](int buf, int isB, int h, int t) {
        const char* g = (isB ? gB0 : gA0) + (long)h * 128 * ld + (long)t * 128;
        char* l = (char*)lds + buf * 65536 + isB * 32768 + h * 16384 + tid * 16;
        gload_lds16(g, l);
        gload_lds16(g + 64 * ld, l + 8192);
    };

    // lane's k-block = lk (32B = chunks 2lk, 2lk+1), XOR-swizzled by row&7
    const int xc0 = ((2 * lk + 0) ^ (l15 & 7)) * 16;
    const int xc1 = ((2 * lk + 1) ^ (l15 & 7)) * 16;
    const int baseA = (wr * 16 + l15) * 128;
    const int baseB = 32768 + (wc * 16 + l15) * 128;

#define LDF8(dst, off) { \
    i32x4 lo_ = *(const i32x4*)(lcur + (off) + xc0); \
    i32x4 hi_ = *(const i32x4*)(lcur + (off) + xc1); \
    dst = __builtin_shufflevector(lo_, hi_, 0, 1, 2, 3, 4, 5, 6, 7); }

    f32x4 acc[8][4];
    #pragma unroll
    for (int i = 0; i < 8; i++)
        #pragma unroll
        for (int j = 0; j < 4; j++) acc[i][j] = f32x4{0.f, 0.f, 0.f, 0.f};

    // prologue: {A0,B0,B1,A1}
    stage(0, 0, 0, 0); stage(0, 1, 0, 0); stage(0, 1, 1, 0); stage(0, 0, 1, 0);
    asm volatile("s_waitcnt vmcnt(4)" ::: "memory");
    __builtin_amdgcn_sched_barrier(0);
    __builtin_amdgcn_s_barrier();

    i32x8 a[4], b[4];
    for (int t = 0; t < NT; ++t) {
        const int cur = t & 1;
        const int nxt = cur ^ 1;
        const bool pf = (t + 1) < NT;
        const char* lcur = (const char*)lds + (cur << 16);

        // phase 0: A-half0 (kf0-3) x B-half0 (j0-1)
        #pragma unroll
        for (int kf = 0; kf < 4; kf++) LDF8(a[kf], baseA + kf * 4096);
        #pragma unroll
        for (int j = 0; j < 2; j++)    LDF8(b[j], baseB + j * 8192);
        if (pf) stage(nxt, 0, 0, t + 1);
        __builtin_amdgcn_s_barrier();
        asm volatile("s_waitcnt lgkmcnt(0)" ::: "memory");
        __builtin_amdgcn_sched_barrier(0);
        __builtin_amdgcn_s_setprio(1);
        #pragma unroll
        for (int j = 0; j < 2; j++)
            #pragma unroll
            for (int kf = 0; kf < 4; kf++) MFMA_F8(acc[kf][j], a[kf], b[j]);
        __builtin_amdgcn_s_setprio(0);
        if (pf) { asm volatile("s_waitcnt vmcnt(4)" ::: "memory"); }
        else    { asm volatile("s_waitcnt vmcnt(2)" ::: "memory"); }
        __builtin_amdgcn_sched_barrier(0);
        __builtin_amdgcn_s_barrier();

        // phase 1: A-half0 x B-half1 (j2-3)
        #pragma unroll
        for (int j = 0; j < 2; j++)    LDF8(b[2 + j], baseB + (2 + j) * 8192);
        if (pf) stage(nxt, 1, 0, t + 1);
        __builtin_amdgcn_s_barrier();
        asm volatile("s_waitcnt lgkmcnt(0)" ::: "memory");
        __builtin_amdgcn_sched_barrier(0);
        __builtin_amdgcn_s_setprio(1);
        #pragma unroll
        for (int j = 0; j < 2; j++)
            #pragma unroll
            for (int kf = 0; kf < 4; kf++) MFMA_F8(acc[kf][2 + j], a[kf], b[2 + j]);
        __builtin_amdgcn_s_setprio(0);
        if (pf) { asm volatile("s_waitcnt vmcnt(4)" ::: "memory"); }
        else    { asm volatile("s_waitcnt vmcnt(0)" ::: "memory"); }
        __builtin_amdgcn_sched_barrier(0);
        __builtin_amdgcn_s_barrier();

        // phase 2: A-half1 (kf4-7) x B-half0
        #pragma unroll
        for (int kf = 0; kf < 4; kf++) LDF8(a[kf], baseA + (4 + kf) * 4096);
        if (pf) stage(nxt, 1, 1, t + 1);
        __builtin_amdgcn_s_barrier();
        asm volatile("s_waitcnt lgkmcnt(0)" ::: "memory");
        __builtin_amdgcn_sched_barrier(0);
        __builtin_amdgcn_s_setprio(1);
        #pragma unroll
        for (int j = 0; j < 2; j++)
            #pragma unroll
            for (int kf = 0; kf < 4; kf++) MFMA_F8(acc[4 + kf][j], a[kf], b[j]);
        __builtin_amdgcn_s_setprio(0);
        __builtin_amdgcn_s_barrier();

        // phase 3: A-half1 x B-half1
        if (pf) stage(nxt, 0, 1, t + 1);
        __builtin_amdgcn_s_barrier();
        __builtin_amdgcn_s_setprio(1);
        #pragma unroll
        for (int j = 0; j < 2; j++)
            #pragma unroll
            for (int kf = 0; kf < 4; kf++) MFMA_F8(acc[4 + kf][2 + j], a[kf], b[2 + j]);
        __builtin_amdgcn_s_setprio(0);
        if (pf) { asm volatile("s_waitcnt vmcnt(4)" ::: "memory"); }
        __builtin_amdgcn_sched_barrier(0);
        __builtin_amdgcn_s_barrier();
    }
#undef LDF8

    #pragma unroll
    for (int kf = 0; kf < 8; kf++) {
        const long m0 = rowM0 + wr * 16 + kf * 32 + lk * 4;
        #pragma unroll
        for (int r = 0; r < 4; r++) {
            const long m = m0 + r;
            #pragma unroll
            for (int j = 0; j < 4; j++) {
                const long n = rowN0 + wc * 16 + j * 64 + l15;
                const float v = acc[kf][j][r] * scale;
                if (nz == 1) Cf[m * (long)ldc + n] += v;
                else atomicAdd(&Cf[m * (long)ldc + n], v);
            }
        }
    }
}

__global__ __launch_bounds__(256)
void k_cast_bf16(const float* __restrict__ in, bf16_t* __restrict__ out, long n)
{
    const long stride = (long)gridDim.x * blockDim.x;
    for (long i = (long)blockIdx.x * blockDim.x + threadIdx.x; i * 4 < n; i += stride) {
        f32x4 v = *reinterpret_cast<const f32x4*>(in + i * 4);
        union { bf16_t h[4]; ushort4 u; } o;
        o.h[0] = __float2bfloat16(v[0]); o.h[1] = __float2bfloat16(v[1]);
        o.h[2] = __float2bfloat16(v[2]); o.h[3] = __float2bfloat16(v[3]);
        *reinterpret_cast<ushort4*>(out + i * 4) = o.u;
    }
}

// Pass 1: row-sum (+ optional col-sum) partials of f32 attn via atomics.
template<bool COLS>
__global__ __launch_bounds__(256)
void k_sums(const float* __restrict__ in, int C,
            float* __restrict__ rowsum, float* __restrict__ colsum)
{
    __shared__ float cpart[16][64];
    __shared__ float rpart[64][17];
    const int tid = threadIdx.x;
    const int tx  = tid & 15;
    const int ty  = tid >> 4;
    const long c0 = (long)blockIdx.x * 64;
    const long r0 = (long)blockIdx.y * 64;

    float cs0 = 0.f, cs1 = 0.f, cs2 = 0.f, cs3 = 0.f;
    #pragma unroll
    for (int i = 0; i < 4; i++) {
        const int r = i * 16 + ty;
        const f32x4 v = *reinterpret_cast<const f32x4*>(&in[(r0 + r) * (long)C + c0 + tx * 4]);
        rpart[r][tx] = v[0] + v[1] + v[2] + v[3];
        cs0 += v[0]; cs1 += v[1]; cs2 += v[2]; cs3 += v[3];
    }
    if (COLS) {
        cpart[ty][tx * 4 + 0] = cs0;
        cpart[ty][tx * 4 + 1] = cs1;
        cpart[ty][tx * 4 + 2] = cs2;
        cpart[ty][tx * 4 + 3] = cs3;
    }
    __syncthreads();
    if (tid < 64) {
        float rs = 0.f;
        #pragma unroll
        for (int k = 0; k < 16; k++) rs += rpart[tid][k];
        atomicAdd(&rowsum[r0 + tid], rs);
        if (COLS) {
            float cs = 0.f;
            #pragma unroll
            for (int k = 0; k < 16; k++) cs += cpart[k][tid];
            atomicAdd(&colsum[c0 + tid], cs);
        }
    }
}

__global__ __launch_bounds__(256)
void k_invscale(float* __restrict__ s, int n, float c)
{
    const int i = blockIdx.x * 256 + threadIdx.x;
    if (i < n) s[i] = c / (s[i] + 1e-7f);
}

// Pass 2: fp8 operands in concat layouts (scales pre-folded incl 2^13 / 2^11).
template<bool TRANS>
__global__ __launch_bounds__(256)
void k_prep2f8(const float* __restrict__ in, int C,
               unsigned char* __restrict__ Aobj, unsigned char* __restrict__ Arel,
               const float* __restrict__ invRow, const float* __restrict__ invCol)
{
    __shared__ float tile[64][65];
    const int tid = threadIdx.x;
    const int tx  = tid & 15;
    const int ty  = tid >> 4;
    const long c0 = (long)blockIdx.x * 64;
    const long r0 = (long)blockIdx.y * 64;

    #pragma unroll
    for (int i = 0; i < 4; i++) {
        const int r = i * 16 + ty;
        const f32x4 v = *reinterpret_cast<const f32x4*>(&in[(r0 + r) * (long)C + c0 + tx * 4]);
        const float sc = invRow[r0 + r];
        *reinterpret_cast<unsigned*>(&Aobj[(r0 + r) * (long)KOBJ + c0 + tx * 4]) =
            pk4_fp8(v[0] * sc, v[1] * sc, v[2] * sc, v[3] * sc);
        if (TRANS) *reinterpret_cast<f32x4*>(&tile[r][tx * 4]) = v;
    }
    if (TRANS) {
        __syncthreads();
        const int rr = tid & 63;
        const int cg = tid >> 6;
        #pragma unroll
        for (int i = 0; i < 16; i++) {
            const int c = cg * 16 + i;
            const float sc = invCol[c0 + c];
            Arel[(c0 + c) * (long)KREL + r0 + rr] = fp8_byte(tile[rr][c] * sc);
        }
    }
}

extern "C" void kernel_launch(void* const* d_in, const int* in_sizes, int n_in,
                              void* d_out, int out_size, void* d_ws, size_t ws_size,
                              hipStream_t stream)
{
    if (n_in < 15) return;
    const float* obj_feats = (const float*)d_in[0];
    const float* rel_feats = (const float*)d_in[1];
    const float* attn_sub  = (const float*)d_in[2];
    const float* attn_obj  = (const float*)d_in[3];
    const float* attn_self = (const float*)d_in[4];
    const float* Wf[5] = { (const float*)d_in[5], (const float*)d_in[7],
                           (const float*)d_in[9], (const float*)d_in[11], (const float*)d_in[13] };
    const float* Bf[5] = { (const float*)d_in[6], (const float*)d_in[8],
                           (const float*)d_in[10], (const float*)d_in[12], (const float*)d_in[14] };

    const int NO = NOBJ, NR = NREL, D = DIM;

    char* w = (char*)d_ws;
    auto take = [&](size_t bytes) { char* p = w; w += bytes; return p; };
    unsigned char* Aobj8  = (unsigned char*)take((size_t)NO * KOBJ);   // [2048][34816] fp8
    unsigned char* Arel8  = (unsigned char*)take((size_t)NR * KREL);   // [16384][4096] fp8
    unsigned char* fcObj8 = (unsigned char*)take((size_t)D * KOBJ);    // [1024][34816] fp8
    unsigned char* fcRel8 = (unsigned char*)take((size_t)D * KREL);    // [1024][4096]  fp8
    bf16_t* xrel_bf = (bf16_t*)take((size_t)NR * D * 2);
    bf16_t* xobj_bf = (bf16_t*)take((size_t)NO * D * 2);
    bf16_t* Wstk01  = (bf16_t*)take((size_t)2 * D * D * 2);
    bf16_t* Wstk234 = (bf16_t*)take((size_t)3 * D * D * 2);
    float*  b01     = (float*)take((size_t)2 * D * 4);
    float*  bstk    = (float*)take((size_t)3 * D * 4);
    float*  sums    = (float*)take((size_t)(3 * NO + 2 * NR) * 4);
    float* invS     = sums;            // 2^13 * (1/3)/(rowsum+eps)
    float* invO     = sums + NO;
    float* invSelf  = sums + 2 * NO;
    float* invTS    = sums + 3 * NO;   // 2^11 * 0.5/(colsum+eps)
    float* invTO    = sums + 3 * NO + NR;
    if ((size_t)(w - (char*)d_ws) > ws_size) return;   // ws too small: fail loudly

    float* x_obj = (float*)d_out;
    float* x_rel = x_obj + (size_t)NO * D;

    hipMemcpyAsync(x_obj, obj_feats, (size_t)NO * D * 4, hipMemcpyDeviceToDevice, stream);
    hipMemcpyAsync(x_rel, rel_feats, (size_t)NR * D * 4, hipMemcpyDeviceToDevice, stream);
    hipMemcpyAsync(b01,     Bf[0], (size_t)D * 4, hipMemcpyDeviceToDevice, stream);
    hipMemcpyAsync(b01 + D, Bf[1], (size_t)D * 4, hipMemcpyDeviceToDevice, stream);
    for (int i = 0; i < 3; i++)
        hipMemcpyAsync(bstk + i * D, Bf[2 + i], (size_t)D * 4, hipMemcpyDeviceToDevice, stream);
    hipMemsetAsync(sums, 0, (size_t)(3 * NO + 2 * NR) * 4, stream);

    auto cast = [&](const float* in, bf16_t* out, long n) {
        long blocks = (n / 4 + 255) / 256; if (blocks > 4096) blocks = 4096;
        k_cast_bf16<<<dim3((unsigned)blocks), dim3(256), 0, stream>>>(in, out, n);
    };
    cast(Wf[0], Wstk01,                 (long)D * D);
    cast(Wf[1], Wstk01 + (size_t)D * D, (long)D * D);
    for (int i = 0; i < 3; i++)
        cast(Wf[2 + i], Wstk234 + (size_t)i * D * D, (long)D * D);

    // pass 1: exact f32 row/col sums
    k_sums<true><<<dim3(NR / 64, NO / 64), dim3(256), 0, stream>>>(attn_sub, NR, invS, invTS);
    k_sums<true><<<dim3(NR / 64, NO / 64), dim3(256), 0, stream>>>(attn_obj, NR, invO, invTO);
    k_sums<false><<<dim3(NO / 64, NO / 64), dim3(256), 0, stream>>>(attn_self, NO, invSelf, nullptr);
    // fold global power-of-2 into the fp8 quantization scale
    k_invscale<<<dim3((3 * NO + 255) / 256), dim3(256), 0, stream>>>(sums, 3 * NO, 8192.f / 3.f);
    k_invscale<<<dim3((2 * NR + 255) / 256), dim3(256), 0, stream>>>(sums + 3 * NO, 2 * NR, 1024.f);

    // pass 2: fp8 operands in concat layouts
    k_prep2f8<true><<<dim3(NR / 64, NO / 64), dim3(256), 0, stream>>>(
        attn_sub, NR, Aobj8, Arel8, invS, invTS);
    k_prep2f8<true><<<dim3(NR / 64, NO / 64), dim3(256), 0, stream>>>(
        attn_obj, NR, Aobj8 + 16384, Arel8 + 2048, invO, invTO);
    k_prep2f8<false><<<dim3(NO / 64, NO / 64), dim3(256), 0, stream>>>(
        attn_self, NO, Aobj8 + 32768, nullptr, invSelf, nullptr);

    for (int step = 0; step < 2; ++step) {
        cast(x_obj, xobj_bf, (long)NO * D);
        cast(x_rel, xrel_bf, (long)NR * D);

        // fcObj cols [0,32768): [f0|f1] = relu([W0;W1] @ xrel^T + b01) -> fp8
        gemm256fc<<<dim3((2 * D / 256) * (NR / 256), 1, 1), dim3(512), 0, stream>>>(
            Wstk01, xrel_bf, 2 * D, NR, D, b01, fcObj8, KOBJ, NR / 256);
        // fcRel [f2|f3] + fcObj col [32768,34816) (f4) -> fp8
        gemm_bt_f234<<<dim3(3 * D / BM, NO / BN, 1), dim3(GT), 0, stream>>>(
            Wstk234, xobj_bf, 3 * D, NO, D, bstk, fcRel8, fcObj8);

        // x_obj += (Aobj8 @ fcObj8^T) * 2^-13
        gemm256f8<<<dim3((NO / 256) * (D / 256), 1, 8), dim3(512), 0, stream>>>(
            Aobj8, fcObj8, NO, D, KOBJ, x_obj, 1.f / 8192.f, D, D / 256);
        // x_rel += (Arel8 @ fcRel8^T) * 2^-11
        gemm256f8<<<dim3((NR / 256) * (D / 256), 1, 1), dim3(512), 0, stream>>>(
            Arel8, fcRel8, NR, D, KREL, x_rel, 1.f / 2048.f, D, D / 256);
    }
}